// Round 2
// baseline (3524.585 us; speedup 1.0000x reference)
//
#include <hip/hip_runtime.h>
#include <hip/hip_bf16.h>
#include <math.h>

constexpr int BATCH = 1024;
typedef __hip_bfloat16 bf16;

// ---------------------------------------------------------------------------
// Fused conv1(3->16,5x5) + relu+bn1 + conv2(16->32,5x5) + relu+bn2 + pool2.
// Block = (image, 13x13 pooled quadrant of the 26x26 pooled output). 256 thr.
// conv1-out tile kept in LDS as bf16; conv1 weights / x-tile share an LDS
// union with conv2 weights (phases are separated by barriers).
// Total LDS: max(13872+4800, 51200) + 28800 + 576 = 80,576 B  (2 blocks/CU)
// ---------------------------------------------------------------------------
__global__ __launch_bounds__(256)
void conv12_fused(const float* __restrict__ x,
                  const float* __restrict__ c1w, const float* __restrict__ c1b,
                  const float* __restrict__ b1s, const float* __restrict__ b1b,
                  const float* __restrict__ b1m, const float* __restrict__ b1v,
                  const float* __restrict__ c2w, const float* __restrict__ c2b,
                  const float* __restrict__ b2s, const float* __restrict__ b2b,
                  const float* __restrict__ b2m, const float* __restrict__ b2v,
                  bf16* __restrict__ out)
{
    __shared__ __align__(16) unsigned char smem[80576];
    float (*s_x)[34][34] = (float (*)[34][34])smem;             // phase A [3][34][34]
    float (*s_w1)[16]    = (float (*)[16])(smem + 13872);       // phase A [75][16]
    float (*s_w2)[32]    = (float (*)[32])smem;                 // phase B [400][32]
    bf16  (*s_c1)[30][30]= (bf16  (*)[30][30])(smem + 51200);   // [16][30][30]
    float* s_bn1 = (float*)(smem + 51200 + 28800);              // [3][16]
    float* s_bn2 = s_bn1 + 48;                                  // [3][32]

    int bid = blockIdx.x;
    const int qx = bid & 1, qy = (bid >> 1) & 1, img = bid >> 2;
    const int tid = threadIdx.x;
    const int oy0 = qy * 26, ox0 = qx * 26;

    // ---- phase A: stage x tile + conv1 weights, compute conv1 -> s_c1 ----
    const float* xI = x + (size_t)img * 3 * 3600;
    for (int idx = tid; idx < 3 * 34 * 34; idx += 256) {
        const int xx = idx % 34; int r = idx / 34;
        const int yy = r % 34; const int c = r / 34;
        s_x[c][yy][xx] = xI[(c * 60 + oy0 + yy) * 60 + ox0 + xx];
    }
    for (int idx = tid; idx < 16 * 75; idx += 256) {
        const int r = idx % 75, oc = idx / 75;
        s_w1[r][oc] = c1w[oc * 75 + r];
    }
    if (tid < 16) {
        const float sc = b1s[tid] * rsqrtf(b1v[tid] + 1e-5f);
        s_bn1[tid] = c1b[tid]; s_bn1[16 + tid] = sc; s_bn1[32 + tid] = b1b[tid] - b1m[tid] * sc;
    }
    if (tid < 32) {
        const float sc = b2s[tid] * rsqrtf(b2v[tid] + 1e-5f);
        s_bn2[tid] = c2b[tid]; s_bn2[32 + tid] = sc; s_bn2[64 + tid] = b2b[tid] - b2m[tid] * sc;
    }
    __syncthreads();

    for (int p = tid; p < 900; p += 256) {
        const int py = p / 30, px = p % 30;
        float acc[16];
        #pragma unroll
        for (int o = 0; o < 16; ++o) acc[o] = s_bn1[o];
        for (int ic = 0; ic < 3; ++ic) {
            #pragma unroll
            for (int ky = 0; ky < 5; ++ky) {
                #pragma unroll
                for (int kx = 0; kx < 5; ++kx) {
                    const float iv = s_x[ic][py + ky][px + kx];
                    const float* wr = s_w1[(ic * 5 + ky) * 5 + kx];
                    #pragma unroll
                    for (int o = 0; o < 16; ++o) acc[o] = fmaf(iv, wr[o], acc[o]);
                }
            }
        }
        #pragma unroll
        for (int o = 0; o < 16; ++o) {
            const float v = fmaxf(acc[o], 0.f) * s_bn1[16 + o] + s_bn1[32 + o];
            s_c1[o][py][px] = __float2bfloat16(v);
        }
    }
    __syncthreads();

    // ---- phase B: re-stage union with conv2 weights, compute conv2+pool ----
    for (int idx = tid; idx < 32 * 400; idx += 256) {
        const int r = idx % 400, oc = idx / 400;
        s_w2[r][oc] = c2w[oc * 400 + r];
    }
    __syncthreads();

    bf16* outI = out + (size_t)img * 32 * 676;
    // 676 items = 169 pooled positions x 4 oc-subgroups (8 oc each).
    // oct = it/169 keeps weight reads wave-uniform (LDS broadcast).
    for (int it = tid; it < 676; it += 256) {
        const int oct = it / 169;
        const int pp  = it - oct * 169;
        const int py = pp / 13, px = pp % 13;
        const int ob = oct * 8;
        float pooled[8];
        #pragma unroll
        for (int o = 0; o < 8; ++o) pooled[o] = -3.4e38f;
        #pragma unroll
        for (int dy = 0; dy < 2; ++dy) {
            #pragma unroll
            for (int dx = 0; dx < 2; ++dx) {
                const int oy = py * 2 + dy, ox = px * 2 + dx;
                float acc[8];
                #pragma unroll
                for (int o = 0; o < 8; ++o) acc[o] = s_bn2[ob + o];
                for (int ic = 0; ic < 16; ++ic) {
                    #pragma unroll
                    for (int ky = 0; ky < 5; ++ky) {
                        #pragma unroll
                        for (int kx = 0; kx < 5; ++kx) {
                            const float iv = __bfloat162float(s_c1[ic][oy + ky][ox + kx]);
                            const float* wr = s_w2[(ic * 5 + ky) * 5 + kx] + ob;
                            #pragma unroll
                            for (int o = 0; o < 8; ++o) acc[o] = fmaf(iv, wr[o], acc[o]);
                        }
                    }
                }
                #pragma unroll
                for (int o = 0; o < 8; ++o) {
                    const float v = fmaxf(acc[o], 0.f) * s_bn2[32 + ob + o] + s_bn2[64 + ob + o];
                    pooled[o] = fmaxf(pooled[o], v);
                }
            }
        }
        const int gy = qy * 13 + py, gx = qx * 13 + px;
        #pragma unroll
        for (int o = 0; o < 8; ++o)
            outI[(size_t)(ob + o) * 676 + gy * 26 + gx] = __float2bfloat16(pooled[o]);
    }
}

// ---------------------------------------------------------------------------
// conv3: 32->64, 3x3, 26->24, pool->12. bf16 in/out. Block = (img, oc-half).
// LDS: s_in bf16 [32][26][26]=43,264 + s_w f32 [288][32]=36,864 + bn = 80,512 B
// Items = 144 pooled pos x 4 subgroups = 576 = 3 x 192 threads (100% util).
// ---------------------------------------------------------------------------
__global__ __launch_bounds__(192)
void conv3_bn_pool(const bf16* __restrict__ in, const float* __restrict__ wgt,
                   const float* __restrict__ cbias,
                   const float* __restrict__ bns, const float* __restrict__ bnb,
                   const float* __restrict__ bnm, const float* __restrict__ bnv,
                   bf16* __restrict__ out)
{
    __shared__ __align__(16) unsigned char smem[80896];
    bf16  (*s_in)[26][26] = (bf16 (*)[26][26])smem;          // [32][26][26]
    float (*s_w)[32]      = (float (*)[32])(smem + 43264);   // [288][32]
    float* s_bn = (float*)(smem + 43264 + 36864);            // [3][32]

    const int ocg = blockIdx.x & 1;
    const int img = blockIdx.x >> 1;
    const int tid = threadIdx.x;

    const uint4* inI = (const uint4*)(in + (size_t)img * 32 * 676);
    uint4* s_flat = (uint4*)smem;
    for (int idx = tid; idx < 32 * 676 * 2 / 16; idx += 192) s_flat[idx] = inI[idx];
    const float* wG = wgt + (size_t)ocg * 32 * 288;
    for (int idx = tid; idx < 32 * 288; idx += 192) {
        const int r = idx % 288, oc = idx / 288;
        s_w[r][oc] = wG[oc * 288 + r];
    }
    if (tid < 32) {
        const int oc = ocg * 32 + tid;
        const float sc = bns[oc] * rsqrtf(bnv[oc] + 1e-5f);
        s_bn[tid] = cbias[oc]; s_bn[32 + tid] = sc; s_bn[64 + tid] = bnb[oc] - bnm[oc] * sc;
    }
    __syncthreads();

    bf16* outI = out + ((size_t)img * 64 + ocg * 32) * 144;
    for (int it = tid; it < 576; it += 192) {
        const int oct = it / 144;
        const int pp  = it - oct * 144;
        const int py = pp / 12, px = pp % 12;
        const int ob = oct * 8;
        float pooled[8];
        #pragma unroll
        for (int o = 0; o < 8; ++o) pooled[o] = -3.4e38f;
        #pragma unroll
        for (int dy = 0; dy < 2; ++dy) {
            #pragma unroll
            for (int dx = 0; dx < 2; ++dx) {
                const int oy = py * 2 + dy, ox = px * 2 + dx;
                float acc[8];
                #pragma unroll
                for (int o = 0; o < 8; ++o) acc[o] = s_bn[ob + o];
                for (int ic = 0; ic < 32; ++ic) {
                    #pragma unroll
                    for (int ky = 0; ky < 3; ++ky) {
                        #pragma unroll
                        for (int kx = 0; kx < 3; ++kx) {
                            const float iv = __bfloat162float(s_in[ic][oy + ky][ox + kx]);
                            const float* wr = s_w[(ic * 3 + ky) * 3 + kx] + ob;
                            #pragma unroll
                            for (int o = 0; o < 8; ++o) acc[o] = fmaf(iv, wr[o], acc[o]);
                        }
                    }
                }
                #pragma unroll
                for (int o = 0; o < 8; ++o) {
                    const float v = fmaxf(acc[o], 0.f) * s_bn[32 + ob + o] + s_bn[64 + ob + o];
                    pooled[o] = fmaxf(pooled[o], v);
                }
            }
        }
        #pragma unroll
        for (int o = 0; o < 8; ++o)
            outI[(size_t)(ob + o) * 144 + py * 12 + px] = __float2bfloat16(pooled[o]);
    }
}

// ---------------------------------------------------------------------------
// conv4: 64->128, 3x3, 12->10, pool->5. bf16 in, f32 out (feeds fc1).
// Block = (img, oc-group of 16), 128 threads; thread = pre-pool position.
// LDS: 18,432 + 36,864 + 6,400 + 192 = 61,888 B (2 blocks/CU).
// ---------------------------------------------------------------------------
__global__ __launch_bounds__(128)
void conv4_bn_pool(const bf16* __restrict__ in, const float* __restrict__ wgt,
                   const float* __restrict__ cbias,
                   const float* __restrict__ bns, const float* __restrict__ bnb,
                   const float* __restrict__ bnm, const float* __restrict__ bnv,
                   float* __restrict__ out)
{
    __shared__ __align__(16) unsigned char smem[62080];
    bf16  (*s_in)[12][12] = (bf16 (*)[12][12])smem;          // [64][12][12]
    float (*s_w)[16]      = (float (*)[16])(smem + 18432);   // [576][16]
    float (*s_pre)[16]    = (float (*)[16])(smem + 18432 + 36864); // [100][16]
    float* s_bn = (float*)(smem + 18432 + 36864 + 6400);     // [3][16]

    const int ocg = blockIdx.x & 7;
    const int img = blockIdx.x >> 3;
    const int tid = threadIdx.x;

    const uint4* inI = (const uint4*)(in + (size_t)img * 64 * 144);
    uint4* s_flat = (uint4*)smem;
    for (int idx = tid; idx < 64 * 144 * 2 / 16; idx += 128) s_flat[idx] = inI[idx];
    const float* wG = wgt + (size_t)ocg * 16 * 576;
    for (int idx = tid; idx < 16 * 576; idx += 128) {
        const int r = idx % 576, oc = idx / 576;
        s_w[r][oc] = wG[oc * 576 + r];
    }
    if (tid < 16) {
        const int oc = ocg * 16 + tid;
        const float sc = bns[oc] * rsqrtf(bnv[oc] + 1e-5f);
        s_bn[tid] = cbias[oc]; s_bn[16 + tid] = sc; s_bn[32 + tid] = bnb[oc] - bnm[oc] * sc;
    }
    __syncthreads();

    if (tid < 100) {
        const int oy = tid / 10, ox = tid % 10;
        float acc[16];
        #pragma unroll
        for (int o = 0; o < 16; ++o) acc[o] = s_bn[o];
        for (int ic = 0; ic < 64; ++ic) {
            #pragma unroll
            for (int ky = 0; ky < 3; ++ky) {
                #pragma unroll
                for (int kx = 0; kx < 3; ++kx) {
                    const float iv = __bfloat162float(s_in[ic][oy + ky][ox + kx]);
                    const float* wr = s_w[(ic * 3 + ky) * 3 + kx];
                    #pragma unroll
                    for (int o = 0; o < 16; ++o) acc[o] = fmaf(iv, wr[o], acc[o]);
                }
            }
        }
        #pragma unroll
        for (int o = 0; o < 16; ++o)
            s_pre[tid][o] = fmaxf(acc[o], 0.f) * s_bn[16 + o] + s_bn[32 + o];
    }
    __syncthreads();
    float* outI = out + (size_t)img * 3200 + ocg * 16 * 25;
    for (int idx = tid; idx < 400; idx += 128) {
        const int o = idx & 15, pp = idx >> 4;
        const int py = pp / 5, px = pp % 5;
        const float a = s_pre[(2 * py) * 10 + 2 * px][o];
        const float b = s_pre[(2 * py) * 10 + 2 * px + 1][o];
        const float c = s_pre[(2 * py + 1) * 10 + 2 * px][o];
        const float d = s_pre[(2 * py + 1) * 10 + 2 * px + 1][o];
        outI[(size_t)o * 25 + py * 5 + px] = fmaxf(fmaxf(a, b), fmaxf(c, d));
    }
}

// ---------------------------------------------------------------------------
// fp32 tiled GEMM: out[M][N] = act(A[M][K] @ W[N][K]^T + bias)
// ---------------------------------------------------------------------------
template<bool RELU>
__global__ __launch_bounds__(256)
void fc_gemm(const float* __restrict__ A, const float* __restrict__ W,
             const float* __restrict__ bias, float* __restrict__ out,
             int M, int N, int K)
{
    constexpr int BK = 32;
    __shared__ float sA[BK][68];
    __shared__ float sB[BK][68];
    const int bn_ = blockIdx.x, bm_ = blockIdx.y;
    const int tid = threadIdx.x;
    const int tn = tid % 16, tm = tid / 16;
    float acc[4][4] = {};
    const float* Ab = A + (size_t)(bm_ * 64) * K;
    const float* Wb = W + (size_t)(bn_ * 64) * K;
    for (int k0 = 0; k0 < K; k0 += BK) {
        #pragma unroll
        for (int i = 0; i < 8; ++i) {
            const int e = tid + i * 256; const int k = e & 31; const int m = e >> 5;
            sA[k][m] = Ab[(size_t)m * K + k0 + k];
        }
        #pragma unroll
        for (int i = 0; i < 8; ++i) {
            const int e = tid + i * 256; const int k = e & 31; const int n = e >> 5;
            sB[k][n] = Wb[(size_t)n * K + k0 + k];
        }
        __syncthreads();
        #pragma unroll
        for (int k = 0; k < BK; ++k) {
            float a[4], b[4];
            #pragma unroll
            for (int i = 0; i < 4; ++i) a[i] = sA[k][tm * 4 + i];
            #pragma unroll
            for (int j = 0; j < 4; ++j) b[j] = sB[k][tn * 4 + j];
            #pragma unroll
            for (int i = 0; i < 4; ++i)
                #pragma unroll
                for (int j = 0; j < 4; ++j) acc[i][j] = fmaf(a[i], b[j], acc[i][j]);
        }
        __syncthreads();
    }
    #pragma unroll
    for (int i = 0; i < 4; ++i) {
        const int row = bm_ * 64 + tm * 4 + i;
        #pragma unroll
        for (int j = 0; j < 4; ++j) {
            const int col = bn_ * 64 + tn * 4 + j;
            float v = acc[i][j] + bias[col];
            if (RELU) v = fmaxf(v, 0.f);
            out[(size_t)row * N + col] = v;
        }
    }
}

// ---------------------------------------------------------------------------
__global__ __launch_bounds__(64)
void fc3_sigmoid(const float* __restrict__ A, const float* __restrict__ W,
                 const float* __restrict__ bias, float* __restrict__ out)
{
    const int row = blockIdx.x;
    const int oc = threadIdx.x;
    if (oc >= 37) return;
    const float* a = A + (size_t)row * 512;
    const float* w = W + (size_t)oc * 512;
    float s = bias[oc];
    for (int k = 0; k < 512; ++k) s = fmaf(a[k], w[k], s);
    out[(size_t)row * 37 + oc] = 1.f / (1.f + expf(-s));
}

// ---------------------------------------------------------------------------
__global__ __launch_bounds__(256)
void norm_mult(float* __restrict__ io)
{
    const int row = blockIdx.x * blockDim.x + threadIdx.x;
    if (row >= BATCH) return;
    float* p = io + (size_t)row * 37;
    float x[37];
    #pragma unroll
    for (int i = 0; i < 37; ++i) x[i] = p[i];
    const int ss[11]  = {0, 3, 5, 7, 9, 13, 15, 18, 25, 28, 31};
    const int ee[11]  = {3, 5, 7, 9, 13, 15, 18, 25, 28, 31, 37};
    const int dep[11] = {-1, 1, 4, 4, 4, -1, 0, 13, 3, 7, 7};
    #pragma unroll
    for (int i = 0; i < 11; ++i) {
        for (int j = ss[i]; j < ee[i]; ++j) {
            float ssum = 0.f;
            for (int c = ss[i]; c < ee[i]; ++c) ssum += x[c];
            x[j] = x[j] / (ssum + 1e-12f);
        }
    }
    #pragma unroll
    for (int i = 0; i < 11; ++i) {
        if (dep[i] >= 0) {
            const float m = x[dep[i]];
            for (int c = ss[i]; c < ee[i]; ++c) x[c] *= m;
        }
    }
    #pragma unroll
    for (int i = 0; i < 37; ++i) p[i] = x[i];
}

// ---------------------------------------------------------------------------
extern "C" void kernel_launch(void* const* d_in, const int* in_sizes, int n_in,
                              void* d_out, int out_size, void* d_ws, size_t ws_size,
                              hipStream_t stream)
{
    const float* x   = (const float*)d_in[0];
    const float* c1w = (const float*)d_in[1];  const float* c1b = (const float*)d_in[2];
    const float* b1s = (const float*)d_in[3];  const float* b1b = (const float*)d_in[4];
    const float* b1m = (const float*)d_in[5];  const float* b1v = (const float*)d_in[6];
    const float* c2w = (const float*)d_in[7];  const float* c2b = (const float*)d_in[8];
    const float* b2s = (const float*)d_in[9];  const float* b2b = (const float*)d_in[10];
    const float* b2m = (const float*)d_in[11]; const float* b2v = (const float*)d_in[12];
    const float* c3w = (const float*)d_in[13]; const float* c3b = (const float*)d_in[14];
    const float* b3s = (const float*)d_in[15]; const float* b3b = (const float*)d_in[16];
    const float* b3m = (const float*)d_in[17]; const float* b3v = (const float*)d_in[18];
    const float* c4w = (const float*)d_in[19]; const float* c4b = (const float*)d_in[20];
    const float* b4s = (const float*)d_in[21]; const float* b4b = (const float*)d_in[22];
    const float* b4m = (const float*)d_in[23]; const float* b4v = (const float*)d_in[24];
    const float* f1w = (const float*)d_in[25]; const float* f1b = (const float*)d_in[26];
    const float* f2w = (const float*)d_in[27]; const float* f2b = (const float*)d_in[28];
    const float* f3w = (const float*)d_in[29]; const float* f3b = (const float*)d_in[30];

    // Workspace layout (bytes), peak 82.6 MB:
    //   P2 bf16 @ 0         : 44,302,336  (conv2 out, 1024x32x26x26)
    //   P3 bf16 @ 44302336  : 18,874,368  (conv3 out, 1024x64x12x12)
    //   P4 f32  @ 63176704  : 13,107,200  (conv4 out, 1024x3200)
    //   F1 f32  @ 76283904  :  4,194,304  (fc1 out, 1024x1024)
    //   F2 f32  @ 80478208  :  2,097,152  (fc2 out, 1024x512)
    bf16*  P2 = (bf16*)d_ws;
    bf16*  P3 = (bf16*)((char*)d_ws + 44302336);
    float* P4 = (float*)((char*)d_ws + 63176704);
    float* F1 = (float*)((char*)d_ws + 76283904);
    float* F2 = (float*)((char*)d_ws + 80478208);

    conv12_fused<<<BATCH * 4, 256, 0, stream>>>(x, c1w, c1b, b1s, b1b, b1m, b1v,
                                                c2w, c2b, b2s, b2b, b2m, b2v, P2);
    conv3_bn_pool<<<BATCH * 2, 192, 0, stream>>>(P2, c3w, c3b, b3s, b3b, b3m, b3v, P3);
    conv4_bn_pool<<<BATCH * 8, 128, 0, stream>>>(P3, c4w, c4b, b4s, b4b, b4m, b4v, P4);

    fc_gemm<true><<<dim3(1024 / 64, 1024 / 64), 256, 0, stream>>>(P4, f1w, f1b, F1, 1024, 1024, 3200);
    fc_gemm<true><<<dim3(512 / 64, 1024 / 64), 256, 0, stream>>>(F1, f2w, f2b, F2, 1024, 512, 1024);
    fc3_sigmoid<<<BATCH, 64, 0, stream>>>(F2, f3w, f3b, (float*)d_out);
    norm_mult<<<(BATCH + 255) / 256, 256, 0, stream>>>((float*)d_out);
}

// Round 3
// 1326.293 us; speedup vs baseline: 2.6575x; 2.6575x over previous
//
#include <hip/hip_runtime.h>
#include <hip/hip_bf16.h>
#include <math.h>

constexpr int BATCH = 1024;
typedef unsigned short u16;
typedef __attribute__((ext_vector_type(8))) short bf16x8;
typedef __attribute__((ext_vector_type(4))) float f32x4;

__device__ __forceinline__ u16 f2bf(float f) {
    union { __hip_bfloat16 b; u16 s; } u; u.b = __float2bfloat16(f); return u.s;
}
__device__ __forceinline__ f32x4 mfma16(bf16x8 a, bf16x8 b, f32x4 c) {
    return __builtin_amdgcn_mfma_f32_16x16x32_bf16(a, b, c, 0, 0, 0);
}

// ---------------------------------------------------------------------------
// conv1 (VALU, 3->16) fused with conv2 (MFMA, 16->32, 5x5) + relu/bn + pool.
// Block = (img, quadrant). M = 676 pre-pool positions in pool-quad order
// (rows 4q+Q, Q=dy*2+dx) so each lane's 4 acc regs form one 2x2 pool window.
// K = 400 reordered cell-major: k = (ky*5+kx)*16 + ic  (8-contig k = 8 ic).
// s_c1 channels-last [900][16] bf16, XOR-swizzled against bank conflicts.
// Output P2: [img][676 pos][32 oc] channels-last bf16.
// ---------------------------------------------------------------------------
__global__ __launch_bounds__(256)
void conv12_fused(const float* __restrict__ x,
                  const float* __restrict__ c1w, const float* __restrict__ c1b,
                  const float* __restrict__ b1s, const float* __restrict__ b1b,
                  const float* __restrict__ b1m, const float* __restrict__ b1v,
                  const float* __restrict__ c2w, const float* __restrict__ c2b,
                  const float* __restrict__ b2s, const float* __restrict__ b2b,
                  const float* __restrict__ b2m, const float* __restrict__ b2v,
                  u16* __restrict__ out)
{
    __shared__ __align__(16) unsigned char S[75184];
    // 0      : s_c1  bf16 [900 pos][16 ic] (swizzled)      28800
    // 28800  : s_w2t bf16 [32 oc][424 k]                   27136
    // 55936  : s_x   f32  [3][34][34]                      13872
    // 69808  : s_w1  f32  [75][16]                          4800
    // 74608  : bn1 f32 [48] ; 74800: bn2 f32 [96]
    u16*  s_w2t = (u16*)(S + 28800);
    float (*s_x)[34][34] = (float(*)[34][34])(S + 55936);
    float (*s_w1)[16]    = (float(*)[16])(S + 69808);
    float* s_bn1 = (float*)(S + 74608);
    float* s_bn2 = (float*)(S + 74800);

    const int tid = threadIdx.x;
    int bid = blockIdx.x;
    const int qx = bid & 1, qy = (bid >> 1) & 1, img = bid >> 2;
    const int oy0 = qy * 26, ox0 = qx * 26;

    // ---- stage x tile, conv1 weights, conv2 weights (transposed k), bn ----
    const float* xI = x + (size_t)img * 3 * 3600;
    for (int idx = tid; idx < 3 * 34 * 34; idx += 256) {
        int xx = idx % 34, r = idx / 34, yy = r % 34, c = r / 34;
        s_x[c][yy][xx] = xI[(c * 60 + oy0 + yy) * 60 + ox0 + xx];
    }
    for (int idx = tid; idx < 75 * 16; idx += 256) {
        int r = idx % 75, oc = idx / 75;
        s_w1[r][oc] = c1w[oc * 75 + r];
    }
    for (int idx = tid; idx < 32 * 424; idx += 256) {
        int k = idx % 424, oc = idx / 424;
        float v = 0.f;
        if (k < 400) v = c2w[(oc * 16 + (k & 15)) * 25 + (k >> 4)];
        s_w2t[oc * 424 + k] = f2bf(v);
    }
    if (tid < 16) {
        float sc = b1s[tid] * rsqrtf(b1v[tid] + 1e-5f);
        s_bn1[tid] = c1b[tid]; s_bn1[16 + tid] = sc; s_bn1[32 + tid] = b1b[tid] - b1m[tid] * sc;
    }
    if (tid < 32) {
        float sc = b2s[tid] * rsqrtf(b2v[tid] + 1e-5f);
        s_bn2[tid] = c2b[tid]; s_bn2[32 + tid] = sc; s_bn2[64 + tid] = b2b[tid] - b2m[tid] * sc;
    }
    __syncthreads();

    // ---- conv1 (VALU) -> s_c1 channels-last bf16, swizzled ----
    for (int p = tid; p < 900; p += 256) {
        int py = p / 30, px = p % 30;
        float acc[16];
        #pragma unroll
        for (int o = 0; o < 16; ++o) acc[o] = s_bn1[o];
        #pragma unroll
        for (int ic = 0; ic < 3; ++ic)
            #pragma unroll
            for (int ky = 0; ky < 5; ++ky)
                #pragma unroll
                for (int kx = 0; kx < 5; ++kx) {
                    float iv = s_x[ic][py + ky][px + kx];
                    const float* wr = s_w1[(ic * 5 + ky) * 5 + kx];
                    #pragma unroll
                    for (int o = 0; o < 16; ++o) acc[o] = fmaf(iv, wr[o], acc[o]);
                }
        bf16x8 lo, hi;
        #pragma unroll
        for (int o = 0; o < 8; ++o) {
            ((u16*)&lo)[o] = f2bf(fmaxf(acc[o], 0.f) * s_bn1[16 + o] + s_bn1[32 + o]);
            ((u16*)&hi)[o] = f2bf(fmaxf(acc[8 + o], 0.f) * s_bn1[24 + o] + s_bn1[40 + o]);
        }
        int swz = (((p >> 2) & 3) << 5) | (((p >> 4) & 1) << 4);
        int base = p * 32;
        *(bf16x8*)(S + ((base + 0) ^ swz)) = lo;
        *(bf16x8*)(S + ((base + 16) ^ swz)) = hi;
    }
    __syncthreads();

    // ---- conv2 via MFMA: 43 M-tiles (688 rows, 172 quads, 3 pad) ----
    const int w  = tid >> 6;
    const int lr = tid & 15;
    const int lg = (tid >> 4) & 3;

    f32x4 acc[11][2];
    #pragma unroll
    for (int mi = 0; mi < 11; ++mi) {
        f32x4 z = {0.f, 0.f, 0.f, 0.f};
        acc[mi][0] = z; acc[mi][1] = z;
    }
    int y2a[11], x2a[11];
    #pragma unroll
    for (int mi = 0; mi < 11; ++mi) {
        int aquad = (w + mi * 4) * 4 + (lr >> 2);
        if (aquad > 168) aquad = 168;
        y2a[mi] = 2 * (aquad / 13) + ((lr >> 1) & 1);
        x2a[mi] = 2 * (aquad % 13) + (lr & 1);
    }
    const int icByte = (lg & 1) * 16;
    for (int ks = 0; ks < 13; ++ks) {
        int kb2 = (ks * 32 + lg * 8) * 2;
        bf16x8 b0 = *(const bf16x8*)(S + 28800 + lr * 848 + kb2);
        bf16x8 b1 = *(const bf16x8*)(S + 28800 + (16 + lr) * 848 + kb2);
        int cell = ks * 2 + (lg >> 1); if (cell > 24) cell = 24;
        int ky = cell / 5, kx = cell % 5;
        #pragma unroll
        for (int mi = 0; mi < 11; ++mi) {
            int pos = (y2a[mi] + ky) * 30 + x2a[mi] + kx;
            int off = (pos * 32 + icByte) ^ ((((pos >> 2) & 3) << 5) | (((pos >> 4) & 1) << 4));
            bf16x8 a = *(const bf16x8*)(S + off);
            acc[mi][0] = mfma16(a, b0, acc[mi][0]);
            acc[mi][1] = mfma16(a, b1, acc[mi][1]);
        }
    }
    // ---- epilogue: bias -> relu -> bn -> in-lane 2x2 pool -> global ----
    u16* outI = out + (size_t)img * 676 * 32;
    float bc0 = s_bn2[lr],      sc0 = s_bn2[32 + lr], sh0 = s_bn2[64 + lr];
    float bc1 = s_bn2[16 + lr], sc1 = s_bn2[48 + lr], sh1 = s_bn2[80 + lr];
    #pragma unroll
    for (int mi = 0; mi < 11; ++mi) {
        int quad = (w + mi * 4) * 4 + lg;
        if (quad < 169) {
            int py = quad / 13, px = quad % 13;
            int gpos = (qy * 13 + py) * 26 + qx * 13 + px;
            float m0 = -3.4e38f, m1 = -3.4e38f;
            #pragma unroll
            for (int r2 = 0; r2 < 4; ++r2) {
                m0 = fmaxf(m0, fmaxf(acc[mi][0][r2] + bc0, 0.f) * sc0 + sh0);
                m1 = fmaxf(m1, fmaxf(acc[mi][1][r2] + bc1, 0.f) * sc1 + sh1);
            }
            outI[gpos * 32 + lr]      = f2bf(m0);
            outI[gpos * 32 + 16 + lr] = f2bf(m1);
        }
    }
}

// ---------------------------------------------------------------------------
// conv3 MFMA: 32->64, 3x3, 26->24, pool->12. Block=(img, oc-half of 32).
// In: P2 [img][676][32] bf16; Out: P3 [img][144][64] bf16 channels-last.
// M = 576 = 36 tiles exactly; K = 288 = 9 steps (k = cell*32 + ic).
// ---------------------------------------------------------------------------
__global__ __launch_bounds__(256)
void conv3_mfma(const u16* __restrict__ in, const float* __restrict__ wgt,
                const float* __restrict__ cbias,
                const float* __restrict__ bns, const float* __restrict__ bnb,
                const float* __restrict__ bnm, const float* __restrict__ bnv,
                u16* __restrict__ out)
{
    __shared__ __align__(16) unsigned char S[62592];
    // 0: s_in [676][32] bf16 swz = 43264 ; 43264: s_w3t [32][296] = 18944 ; 62208: bn[96]
    u16* s_w3t = (u16*)(S + 43264);
    float* s_bn = (float*)(S + 62208);

    const int tid = threadIdx.x;
    const int ocg = blockIdx.x & 1;
    const int img = blockIdx.x >> 1;

    const u16* inI = in + (size_t)img * 676 * 32;
    for (int g = tid; g < 676 * 4; g += 256) {
        int pos = g >> 2, part = g & 3;
        int off = (pos * 64 + part * 16) ^ (((pos >> 1) & 7) << 4);
        *(bf16x8*)(S + off) = *(const bf16x8*)(inI + g * 8);
    }
    for (int idx = tid; idx < 32 * 296; idx += 256) {
        int k = idx % 296, oc = idx / 296;
        float v = 0.f;
        if (k < 288) v = wgt[((ocg * 32 + oc) * 32 + (k & 31)) * 9 + (k >> 5)];
        s_w3t[oc * 296 + k] = f2bf(v);
    }
    if (tid < 32) {
        int oc = ocg * 32 + tid;
        float sc = bns[oc] * rsqrtf(bnv[oc] + 1e-5f);
        s_bn[tid] = cbias[oc]; s_bn[32 + tid] = sc; s_bn[64 + tid] = bnb[oc] - bnm[oc] * sc;
    }
    __syncthreads();

    const int w = tid >> 6, lr = tid & 15, lg = (tid >> 4) & 3;
    f32x4 acc[9][2];
    #pragma unroll
    for (int mi = 0; mi < 9; ++mi) {
        f32x4 z = {0.f, 0.f, 0.f, 0.f};
        acc[mi][0] = z; acc[mi][1] = z;
    }
    int y2a[9], x2a[9];
    #pragma unroll
    for (int mi = 0; mi < 9; ++mi) {
        int aquad = (w + mi * 4) * 4 + (lr >> 2);   // < 144 always
        y2a[mi] = 2 * (aquad / 12) + ((lr >> 1) & 1);
        x2a[mi] = 2 * (aquad % 12) + (lr & 1);
    }
    const int icb = lg * 16;
    for (int ks = 0; ks < 9; ++ks) {
        int kb2 = (ks * 32 + lg * 8) * 2;
        bf16x8 b0 = *(const bf16x8*)(S + 43264 + lr * 592 + kb2);
        bf16x8 b1 = *(const bf16x8*)(S + 43264 + (16 + lr) * 592 + kb2);
        int ky = ks / 3, kx = ks % 3;
        #pragma unroll
        for (int mi = 0; mi < 9; ++mi) {
            int pos = (y2a[mi] + ky) * 26 + x2a[mi] + kx;
            int off = (pos * 64 + icb) ^ (((pos >> 1) & 7) << 4);
            bf16x8 a = *(const bf16x8*)(S + off);
            acc[mi][0] = mfma16(a, b0, acc[mi][0]);
            acc[mi][1] = mfma16(a, b1, acc[mi][1]);
        }
    }
    u16* outI = out + (size_t)img * 144 * 64 + ocg * 32;
    float bc0 = s_bn[lr],      sc0 = s_bn[32 + lr], sh0 = s_bn[64 + lr];
    float bc1 = s_bn[16 + lr], sc1 = s_bn[48 + lr], sh1 = s_bn[80 + lr];
    #pragma unroll
    for (int mi = 0; mi < 9; ++mi) {
        int quad = (w + mi * 4) * 4 + lg;            // < 144
        float m0 = -3.4e38f, m1 = -3.4e38f;
        #pragma unroll
        for (int r2 = 0; r2 < 4; ++r2) {
            m0 = fmaxf(m0, fmaxf(acc[mi][0][r2] + bc0, 0.f) * sc0 + sh0);
            m1 = fmaxf(m1, fmaxf(acc[mi][1][r2] + bc1, 0.f) * sc1 + sh1);
        }
        outI[quad * 64 + lr]      = f2bf(m0);
        outI[quad * 64 + 16 + lr] = f2bf(m1);
    }
}

// ---------------------------------------------------------------------------
// conv4 MFMA: 64->128, 3x3, 12->10, pool->5. Block=(img, oc-quarter of 32).
// In: P3 [img][144][64]; Out: P4 [img][3200] bf16 with k = oc*25 + (py*5+px).
// M = 100 -> 7 tiles (112 rows, pad); K = 576 = 18 steps (k = cell*64 + ic).
// ---------------------------------------------------------------------------
__global__ __launch_bounds__(256)
void conv4_mfma(const u16* __restrict__ in, const float* __restrict__ wgt,
                const float* __restrict__ cbias,
                const float* __restrict__ bns, const float* __restrict__ bnb,
                const float* __restrict__ bnm, const float* __restrict__ bnv,
                u16* __restrict__ out)
{
    __shared__ __align__(16) unsigned char S[56192];
    // 0: s_in [144][64] = 18432 ; 18432: s_w4t [32][584] = 37376 ; 55808: bn[96]
    u16* s_w4t = (u16*)(S + 18432);
    float* s_bn = (float*)(S + 55808);

    const int tid = threadIdx.x;
    const int ocg = blockIdx.x & 3;
    const int img = blockIdx.x >> 2;

    const u16* inI = in + (size_t)img * 144 * 64;
    for (int g = tid; g < 144 * 8; g += 256) {
        int pos = g >> 3, part = g & 7;
        int off = (pos * 128 + part * 16) ^ ((pos & 7) << 4);
        *(bf16x8*)(S + off) = *(const bf16x8*)(inI + g * 8);
    }
    for (int idx = tid; idx < 32 * 584; idx += 256) {
        int k = idx % 584, oc = idx / 584;
        float v = 0.f;
        if (k < 576) v = wgt[((ocg * 32 + oc) * 64 + (k & 63)) * 9 + (k >> 6)];
        s_w4t[oc * 584 + k] = f2bf(v);
    }
    if (tid < 32) {
        int oc = ocg * 32 + tid;
        float sc = bns[oc] * rsqrtf(bnv[oc] + 1e-5f);
        s_bn[tid] = cbias[oc]; s_bn[32 + tid] = sc; s_bn[64 + tid] = bnb[oc] - bnm[oc] * sc;
    }
    __syncthreads();

    const int w = tid >> 6, lr = tid & 15, lg = (tid >> 4) & 3;
    f32x4 acc[2][2];
    {
        f32x4 z = {0.f, 0.f, 0.f, 0.f};
        acc[0][0] = z; acc[0][1] = z; acc[1][0] = z; acc[1][1] = z;
    }
    int y2a[2], x2a[2];
    #pragma unroll
    for (int mi = 0; mi < 2; ++mi) {
        int aquad = (w + mi * 4) * 4 + (lr >> 2);
        if (aquad > 24) aquad = 24;
        y2a[mi] = 2 * (aquad / 5) + ((lr >> 1) & 1);
        x2a[mi] = 2 * (aquad % 5) + (lr & 1);
    }
    for (int ks = 0; ks < 18; ++ks) {
        int kb2 = (ks * 32 + lg * 8) * 2;
        bf16x8 b0 = *(const bf16x8*)(S + 18432 + lr * 1168 + kb2);
        bf16x8 b1 = *(const bf16x8*)(S + 18432 + (16 + lr) * 1168 + kb2);
        int cell = ks >> 1;
        int ky = cell / 3, kx = cell % 3;
        int icb = (ks & 1) * 64 + lg * 16;
        #pragma unroll
        for (int mi = 0; mi < 2; ++mi) {
            int pos = (y2a[mi] + ky) * 12 + x2a[mi] + kx;
            int off = (pos * 128 + icb) ^ ((pos & 7) << 4);
            bf16x8 a = *(const bf16x8*)(S + off);
            acc[mi][0] = mfma16(a, b0, acc[mi][0]);
            acc[mi][1] = mfma16(a, b1, acc[mi][1]);
        }
    }
    u16* outI = out + (size_t)img * 3200;
    float bc0 = s_bn[lr],      sc0 = s_bn[32 + lr], sh0 = s_bn[64 + lr];
    float bc1 = s_bn[16 + lr], sc1 = s_bn[48 + lr], sh1 = s_bn[80 + lr];
    #pragma unroll
    for (int mi = 0; mi < 2; ++mi) {
        int quad = (w + mi * 4) * 4 + lg;
        if (quad < 25) {
            float m0 = -3.4e38f, m1 = -3.4e38f;
            #pragma unroll
            for (int r2 = 0; r2 < 4; ++r2) {
                m0 = fmaxf(m0, fmaxf(acc[mi][0][r2] + bc0, 0.f) * sc0 + sh0);
                m1 = fmaxf(m1, fmaxf(acc[mi][1][r2] + bc1, 0.f) * sc1 + sh1);
            }
            outI[(ocg * 32 + lr) * 25 + quad]      = f2bf(m0);
            outI[(ocg * 32 + 16 + lr) * 25 + quad] = f2bf(m1);
        }
    }
}

// ---------------------------------------------------------------------------
// fc MFMA GEMM: out = relu(A[M][K](bf16) @ W[N][K]^T(f32->bf16) + bias).
// 64x64 tile, 256 thr = 4 waves, each wave one 16-row slab x 64 cols.
// ---------------------------------------------------------------------------
template<bool OUTF32>
__global__ __launch_bounds__(256)
void fc_mfma(const u16* __restrict__ A, const float* __restrict__ Wt,
             const float* __restrict__ bias, void* __restrict__ outv,
             int M, int N, int K)
{
    __shared__ __align__(16) unsigned char S[10240];
    const int tid = threadIdx.x;
    const int n0 = blockIdx.x * 64, m0 = blockIdx.y * 64;
    const int w = tid >> 6, lr = tid & 15, lg = (tid >> 4) & 3;
    const int srow = tid >> 2, spart = tid & 3;

    f32x4 acc[4];
    {
        f32x4 z = {0.f, 0.f, 0.f, 0.f};
        acc[0] = z; acc[1] = z; acc[2] = z; acc[3] = z;
    }
    for (int k0 = 0; k0 < K; k0 += 32) {
        *(bf16x8*)(S + srow * 80 + spart * 16) =
            *(const bf16x8*)(A + (size_t)(m0 + srow) * K + k0 + spart * 8);
        const float* wsrc = Wt + (size_t)(n0 + srow) * K + k0 + spart * 8;
        bf16x8 bv;
        #pragma unroll
        for (int j = 0; j < 8; ++j) ((u16*)&bv)[j] = f2bf(wsrc[j]);
        *(bf16x8*)(S + 5120 + srow * 80 + spart * 16) = bv;
        __syncthreads();
        bf16x8 af = *(const bf16x8*)(S + (w * 16 + lr) * 80 + lg * 16);
        #pragma unroll
        for (int nt = 0; nt < 4; ++nt) {
            bf16x8 bfr = *(const bf16x8*)(S + 5120 + (nt * 16 + lr) * 80 + lg * 16);
            acc[nt] = mfma16(af, bfr, acc[nt]);
        }
        __syncthreads();
    }
    #pragma unroll
    for (int nt = 0; nt < 4; ++nt) {
        int col = n0 + nt * 16 + lr;
        float bv = bias[col];
        #pragma unroll
        for (int r2 = 0; r2 < 4; ++r2) {
            int row = m0 + w * 16 + lg * 4 + r2;
            float v = fmaxf(acc[nt][r2] + bv, 0.f);
            if (OUTF32) ((float*)outv)[(size_t)row * N + col] = v;
            else        ((u16*)outv)[(size_t)row * N + col] = f2bf(v);
        }
    }
}

// ---------------------------------------------------------------------------
// fc3 (512->37) + sigmoid. Block per image; A-row staged in LDS as float4.
// ---------------------------------------------------------------------------
__global__ __launch_bounds__(64)
void fc3_sigmoid(const float* __restrict__ A, const float* __restrict__ W,
                 const float* __restrict__ bias, float* __restrict__ out)
{
    __shared__ float4 sa[128];
    const int img = blockIdx.x, t = threadIdx.x;
    const float4* Ar = (const float4*)(A + (size_t)img * 512);
    sa[t] = Ar[t]; sa[t + 64] = Ar[t + 64];
    __syncthreads();
    if (t < 37) {
        const float4* w4 = (const float4*)(W + (size_t)t * 512);
        float s = bias[t];
        #pragma unroll 4
        for (int k = 0; k < 128; ++k) {
            float4 a = sa[k], ww = w4[k];
            s = fmaf(a.x, ww.x, s); s = fmaf(a.y, ww.y, s);
            s = fmaf(a.z, ww.z, s); s = fmaf(a.w, ww.w, s);
        }
        out[(size_t)img * 37 + t] = 1.f / (1.f + expf(-s));
    }
}

// ---------------------------------------------------------------------------
// Sequential normalize + dependency-multiply, exact reference semantics.
// ---------------------------------------------------------------------------
__global__ __launch_bounds__(256)
void norm_mult(float* __restrict__ io)
{
    const int row = blockIdx.x * blockDim.x + threadIdx.x;
    if (row >= BATCH) return;
    float* p = io + (size_t)row * 37;
    float x[37];
    #pragma unroll
    for (int i = 0; i < 37; ++i) x[i] = p[i];
    const int ss[11]  = {0, 3, 5, 7, 9, 13, 15, 18, 25, 28, 31};
    const int ee[11]  = {3, 5, 7, 9, 13, 15, 18, 25, 28, 31, 37};
    const int dep[11] = {-1, 1, 4, 4, 4, -1, 0, 13, 3, 7, 7};
    #pragma unroll
    for (int i = 0; i < 11; ++i) {
        for (int j = ss[i]; j < ee[i]; ++j) {
            float ssum = 0.f;
            for (int c = ss[i]; c < ee[i]; ++c) ssum += x[c];
            x[j] = x[j] / (ssum + 1e-12f);
        }
    }
    #pragma unroll
    for (int i = 0; i < 11; ++i) {
        if (dep[i] >= 0) {
            const float m = x[dep[i]];
            for (int c = ss[i]; c < ee[i]; ++c) x[c] *= m;
        }
    }
    #pragma unroll
    for (int i = 0; i < 37; ++i) p[i] = x[i];
}

// ---------------------------------------------------------------------------
extern "C" void kernel_launch(void* const* d_in, const int* in_sizes, int n_in,
                              void* d_out, int out_size, void* d_ws, size_t ws_size,
                              hipStream_t stream)
{
    const float* x   = (const float*)d_in[0];
    const float* c1w = (const float*)d_in[1];  const float* c1b = (const float*)d_in[2];
    const float* b1s = (const float*)d_in[3];  const float* b1b = (const float*)d_in[4];
    const float* b1m = (const float*)d_in[5];  const float* b1v = (const float*)d_in[6];
    const float* c2w = (const float*)d_in[7];  const float* c2b = (const float*)d_in[8];
    const float* b2s = (const float*)d_in[9];  const float* b2b = (const float*)d_in[10];
    const float* b2m = (const float*)d_in[11]; const float* b2v = (const float*)d_in[12];
    const float* c3w = (const float*)d_in[13]; const float* c3b = (const float*)d_in[14];
    const float* b3s = (const float*)d_in[15]; const float* b3b = (const float*)d_in[16];
    const float* b3m = (const float*)d_in[17]; const float* b3v = (const float*)d_in[18];
    const float* c4w = (const float*)d_in[19]; const float* c4b = (const float*)d_in[20];
    const float* b4s = (const float*)d_in[21]; const float* b4b = (const float*)d_in[22];
    const float* b4m = (const float*)d_in[23]; const float* b4v = (const float*)d_in[24];
    const float* f1w = (const float*)d_in[25]; const float* f1b = (const float*)d_in[26];
    const float* f2w = (const float*)d_in[27]; const float* f2b = (const float*)d_in[28];
    const float* f3w = (const float*)d_in[29]; const float* f3b = (const float*)d_in[30];

    // Workspace (bytes), peak 73.9 MB:
    //   P2 bf16 [1024][676][32]  @ 0          44,302,336
    //   P3 bf16 [1024][144][64]  @ 44,302,336 18,874,368
    //   P4 bf16 [1024][3200]     @ 63,176,704  6,553,600
    //   F1 bf16 [1024][1024]     @ 69,730,304  2,097,152
    //   F2 f32  [1024][512]      @ 71,827,456  2,097,152
    u16*   P2 = (u16*)d_ws;
    u16*   P3 = (u16*)((char*)d_ws + 44302336);
    u16*   P4 = (u16*)((char*)d_ws + 63176704);
    u16*   F1 = (u16*)((char*)d_ws + 69730304);
    float* F2 = (float*)((char*)d_ws + 71827456);

    conv12_fused<<<BATCH * 4, 256, 0, stream>>>(x, c1w, c1b, b1s, b1b, b1m, b1v,
                                                c2w, c2b, b2s, b2b, b2m, b2v, P2);
    conv3_mfma<<<BATCH * 2, 256, 0, stream>>>(P2, c3w, c3b, b3s, b3b, b3m, b3v, P3);
    conv4_mfma<<<BATCH * 4, 256, 0, stream>>>(P3, c4w, c4b, b4s, b4b, b4m, b4v, P4);

    fc_mfma<false><<<dim3(16, 16), 256, 0, stream>>>(P4, f1w, f1b, F1, 1024, 1024, 3200);
    fc_mfma<true ><<<dim3(8, 16),  256, 0, stream>>>(F1, f2w, f2b, F2, 1024, 512, 1024);
    fc3_sigmoid<<<BATCH, 64, 0, stream>>>(F2, f3w, f3b, (float*)d_out);
    norm_mult<<<(BATCH + 255) / 256, 256, 0, stream>>>((float*)d_out);
}

// Round 4
// 417.339 us; speedup vs baseline: 8.4454x; 3.1780x over previous
//
#include <hip/hip_runtime.h>
#include <hip/hip_bf16.h>
#include <math.h>

constexpr int BATCH = 1024;
typedef unsigned short u16;
typedef __attribute__((ext_vector_type(8))) short bf16x8;
typedef __attribute__((ext_vector_type(4))) float f32x4;

__device__ __forceinline__ u16 f2bf(float f) {
    union { __hip_bfloat16 b; u16 s; } u; u.b = __float2bfloat16(f); return u.s;
}
__device__ __forceinline__ f32x4 mfma16(bf16x8 a, bf16x8 b, f32x4 c) {
    return __builtin_amdgcn_mfma_f32_16x16x32_bf16(a, b, c, 0, 0, 0);
}

// ---------------------------------------------------------------------------
// Fully-MFMA fused conv1(3->16,5x5,VALU->MFMA) + bn1 + conv2(16->32,5x5) +
// bn2 + pool. Block = (img, quadrant), 512 threads = 8 waves.
// conv1: A = x-tile bf16 [34][34][4ic] (k = tap*4+ic, K=128 padded),
//        M = 900 c1 positions (57 tiles), N = 16.
// conv2: A = s_c1 [900][16ic] swizzled (k = tap*16+ic, K=416 padded),
//        M = 676 pre-pool positions quad-major (43 tiles), N = 32.
// In-lane 2x2 pooling via C-layout rows (quad*4 + dy*2+dx).
// LDS: s_c1 28800 | union{s_x 9248 + s_w1 4096 , s_w2t 27136} | bn 576
//    = 56,512 B -> 2 blocks/CU, 16 waves/CU.
// ---------------------------------------------------------------------------
__global__ __launch_bounds__(512, 4)
void conv12_fused(const float* __restrict__ x,
                  const float* __restrict__ c1w, const float* __restrict__ c1b,
                  const float* __restrict__ b1s, const float* __restrict__ b1b,
                  const float* __restrict__ b1m, const float* __restrict__ b1v,
                  const float* __restrict__ c2w, const float* __restrict__ c2b,
                  const float* __restrict__ b2s, const float* __restrict__ b2b,
                  const float* __restrict__ b2m, const float* __restrict__ b2v,
                  u16* __restrict__ out)
{
    __shared__ __align__(16) unsigned char S[56512];
    constexpr int U = 28800;                 // union region base
    float* s_bn1 = (float*)(S + 55936);      // [48]
    float* s_bn2 = (float*)(S + 55936 + 192);// [96]

    const int tid = threadIdx.x;
    int bid = blockIdx.x;
    const int qx = bid & 1, qy = (bid >> 1) & 1, img = bid >> 2;

    // ---- phase 0: stage x-tile (f32->bf16 ic-minor), conv1 weights, bn ----
    const float* xI = x + (size_t)img * 10800 + (qy * 26) * 60 + qx * 26;
    for (int i = tid; i < 34 * 34; i += 512) {
        int yy = i / 34, xx = i - yy * 34;
        const float* p = xI + yy * 60 + xx;
        u16 pk[4];
        pk[0] = f2bf(p[0]); pk[1] = f2bf(p[3600]); pk[2] = f2bf(p[7200]); pk[3] = 0;
        *(unsigned long long*)(S + U + i * 8) = *(unsigned long long*)pk;
    }
    for (int i = tid; i < 256; i += 512) {   // s_w1 [16 oc][128 k], k=tap*4+ic
        int oc = i >> 4, g = i & 15;
        u16 t8[8];
        #pragma unroll
        for (int j = 0; j < 8; ++j) {
            int k = g * 8 + j, tap = k >> 2, ic = k & 3;
            t8[j] = (ic < 3 && tap < 25) ? f2bf(c1w[oc * 75 + ic * 25 + tap]) : (u16)0;
        }
        *(bf16x8*)(S + U + 9248 + oc * 256 + g * 16) = *(bf16x8*)t8;
    }
    if (tid < 16) {
        float sc = b1s[tid] * rsqrtf(b1v[tid] + 1e-5f);
        s_bn1[tid] = c1b[tid]; s_bn1[16 + tid] = sc; s_bn1[32 + tid] = b1b[tid] - b1m[tid] * sc;
    } else if (tid >= 32 && tid < 64) {
        int t = tid - 32;
        float sc = b2s[t] * rsqrtf(b2v[t] + 1e-5f);
        s_bn2[t] = c2b[t]; s_bn2[32 + t] = sc; s_bn2[64 + t] = b2b[t] - b2m[t] * sc;
    }
    __syncthreads();

    const int wv = tid >> 6, lr = tid & 15, lg = (tid >> 4) & 3;

    // ---- conv1 via MFMA -> s_c1 (swizzled channels-last bf16) ----
    {
        int toff[4][2];
        #pragma unroll
        for (int ks = 0; ks < 4; ++ks)
            #pragma unroll
            for (int h = 0; h < 2; ++h) {
                int t = ks * 8 + lg * 2 + h; if (t > 24) t = 24;
                int ky = t / 5;
                toff[ks][h] = (ky * 34 + (t - ky * 5)) * 8;
            }
        bf16x8 wb[4];
        #pragma unroll
        for (int ks = 0; ks < 4; ++ks)
            wb[ks] = *(const bf16x8*)(S + U + 9248 + lr * 256 + ks * 64 + lg * 16);
        float bc = s_bn1[lr], sc = s_bn1[16 + lr], sh = s_bn1[32 + lr];
        #pragma unroll
        for (int mi = 0; mi < 8; ++mi) {
            int t = wv + mi * 8;
            if (t < 57) {
                int pos = t * 16 + lr; if (pos > 899) pos = 899;
                int py = pos / 30;
                int pb = (py * 34 + (pos - py * 30)) * 8;
                f32x4 a = {0.f, 0.f, 0.f, 0.f};
                #pragma unroll
                for (int ks = 0; ks < 4; ++ks) {
                    union { unsigned long long v[2]; bf16x8 f; } af;
                    af.v[0] = *(const unsigned long long*)(S + U + pb + toff[ks][0]);
                    af.v[1] = *(const unsigned long long*)(S + U + pb + toff[ks][1]);
                    a = mfma16(af.f, wb[ks], a);
                }
                int swz = (((t * 4 + lg) & 3) << 5) | ((t & 1) << 4);
                int pw0 = t * 16 + lg * 4;
                #pragma unroll
                for (int r = 0; r < 4; ++r) {
                    int pw = pw0 + r;
                    if (pw < 900) {
                        float v = fmaxf(a[r] + bc, 0.f) * sc + sh;
                        *(u16*)(S + ((pw * 32 + lr * 2) ^ swz)) = f2bf(v);
                    }
                }
            }
        }
    }
    __syncthreads();

    // ---- stage conv2 weights over the union region: [32 oc][424 k] ----
    for (int i = tid; i < 32 * 53; i += 512) {
        int oc = i / 53, g = i - (i / 53) * 53;
        u16 t8[8];
        #pragma unroll
        for (int j = 0; j < 8; ++j) {
            int k = g * 8 + j;
            t8[j] = (k < 400) ? f2bf(c2w[oc * 400 + (k & 15) * 25 + (k >> 4)]) : (u16)0;
        }
        *(bf16x8*)(S + U + oc * 848 + g * 16) = *(bf16x8*)t8;
    }
    __syncthreads();

    // ---- conv2 via MFMA: 43 M-tiles, NT=6 per wave ----
    f32x4 acc[6][2];
    #pragma unroll
    for (int mi = 0; mi < 6; ++mi) { f32x4 z = {0.f,0.f,0.f,0.f}; acc[mi][0] = z; acc[mi][1] = z; }
    int y2a[6], x2a[6];
    #pragma unroll
    for (int mi = 0; mi < 6; ++mi) {
        int t = wv + mi * 8; if (t > 42) t = 42;
        int aq = t * 4 + (lr >> 2); if (aq > 168) aq = 168;
        int pyq = aq / 13;
        y2a[mi] = 2 * pyq + ((lr >> 1) & 1);
        x2a[mi] = 2 * (aq - pyq * 13) + (lr & 1);
    }
    const int icb = (lg & 1) * 16;
    for (int ks = 0; ks < 13; ++ks) {
        bf16x8 b0 = *(const bf16x8*)(S + U + lr * 848 + ks * 64 + lg * 16);
        bf16x8 b1 = *(const bf16x8*)(S + U + (16 + lr) * 848 + ks * 64 + lg * 16);
        int cell = ks * 2 + (lg >> 1); if (cell > 24) cell = 24;
        int ky = cell / 5, kx = cell - (cell / 5) * 5;
        #pragma unroll
        for (int mi = 0; mi < 6; ++mi) {
            int t = wv + mi * 8;
            if (t < 43) {
                int pos = (y2a[mi] + ky) * 30 + x2a[mi] + kx;
                int off = (pos * 32 + icb) ^ ((((pos >> 2) & 3) << 5) | (((pos >> 4) & 1) << 4));
                bf16x8 a = *(const bf16x8*)(S + off);
                acc[mi][0] = mfma16(a, b0, acc[mi][0]);
                acc[mi][1] = mfma16(a, b1, acc[mi][1]);
            }
        }
    }
    // ---- epilogue: bias -> relu -> bn -> in-lane 2x2 pool -> global ----
    u16* outI = out + (size_t)img * 676 * 32;
    float bcA = s_bn2[lr],      scA = s_bn2[32 + lr], shA = s_bn2[64 + lr];
    float bcB = s_bn2[16 + lr], scB = s_bn2[48 + lr], shB = s_bn2[80 + lr];
    #pragma unroll
    for (int mi = 0; mi < 6; ++mi) {
        int t = wv + mi * 8;
        if (t < 43) {
            int quad = t * 4 + lg;
            if (quad < 169) {
                int py = quad / 13, px = quad - (quad / 13) * 13;
                int gpos = (qy * 13 + py) * 26 + qx * 13 + px;
                float m0 = -3.4e38f, m1 = -3.4e38f;
                #pragma unroll
                for (int r = 0; r < 4; ++r) {
                    m0 = fmaxf(m0, fmaxf(acc[mi][0][r] + bcA, 0.f) * scA + shA);
                    m1 = fmaxf(m1, fmaxf(acc[mi][1][r] + bcB, 0.f) * scB + shB);
                }
                outI[gpos * 32 + lr]      = f2bf(m0);
                outI[gpos * 32 + 16 + lr] = f2bf(m1);
            }
        }
    }
}

// ---------------------------------------------------------------------------
// conv3 MFMA: 32->64, 3x3, 26->24, pool->12. Block=(img, oc-half), 512 thr.
// 36 M-tiles, NT=5 per wave with guard.
// ---------------------------------------------------------------------------
__global__ __launch_bounds__(512, 4)
void conv3_mfma(const u16* __restrict__ in, const float* __restrict__ wgt,
                const float* __restrict__ cbias,
                const float* __restrict__ bns, const float* __restrict__ bnb,
                const float* __restrict__ bnm, const float* __restrict__ bnv,
                u16* __restrict__ out)
{
    __shared__ __align__(16) unsigned char S[62592];
    float* s_bn = (float*)(S + 62208);

    const int tid = threadIdx.x;
    const int ocg = blockIdx.x & 1;
    const int img = blockIdx.x >> 1;

    const u16* inI = in + (size_t)img * 676 * 32;
    for (int g = tid; g < 676 * 4; g += 512) {
        int pos = g >> 2, part = g & 3;
        int off = (pos * 64 + part * 16) ^ (((pos >> 1) & 7) << 4);
        *(bf16x8*)(S + off) = *(const bf16x8*)(inI + g * 8);
    }
    for (int i = tid; i < 32 * 37; i += 512) {    // w3t [32][296], k=cell*32+ic
        int oc = i / 37, g = i - (i / 37) * 37;
        u16 t8[8];
        #pragma unroll
        for (int j = 0; j < 8; ++j) {
            int k = g * 8 + j;
            t8[j] = (k < 288) ? f2bf(wgt[((ocg * 32 + oc) * 32 + (k & 31)) * 9 + (k >> 5)]) : (u16)0;
        }
        *(bf16x8*)(S + 43264 + oc * 592 + g * 16) = *(bf16x8*)t8;
    }
    if (tid < 32) {
        int oc = ocg * 32 + tid;
        float sc = bns[oc] * rsqrtf(bnv[oc] + 1e-5f);
        s_bn[tid] = cbias[oc]; s_bn[32 + tid] = sc; s_bn[64 + tid] = bnb[oc] - bnm[oc] * sc;
    }
    __syncthreads();

    const int wv = tid >> 6, lr = tid & 15, lg = (tid >> 4) & 3;
    f32x4 acc[5][2];
    #pragma unroll
    for (int mi = 0; mi < 5; ++mi) { f32x4 z = {0.f,0.f,0.f,0.f}; acc[mi][0] = z; acc[mi][1] = z; }
    int y2a[5], x2a[5];
    #pragma unroll
    for (int mi = 0; mi < 5; ++mi) {
        int t = wv + mi * 8; if (t > 35) t = 35;
        int aq = t * 4 + (lr >> 2);               // < 144
        int pyq = aq / 12;
        y2a[mi] = 2 * pyq + ((lr >> 1) & 1);
        x2a[mi] = 2 * (aq - pyq * 12) + (lr & 1);
    }
    const int icb = lg * 16;
    for (int ks = 0; ks < 9; ++ks) {
        bf16x8 b0 = *(const bf16x8*)(S + 43264 + lr * 592 + ks * 64 + lg * 16);
        bf16x8 b1 = *(const bf16x8*)(S + 43264 + (16 + lr) * 592 + ks * 64 + lg * 16);
        int ky = ks / 3, kx = ks - (ks / 3) * 3;
        #pragma unroll
        for (int mi = 0; mi < 5; ++mi) {
            int t = wv + mi * 8;
            if (t < 36) {
                int pos = (y2a[mi] + ky) * 26 + x2a[mi] + kx;
                int off = (pos * 64 + icb) ^ (((pos >> 1) & 7) << 4);
                bf16x8 a = *(const bf16x8*)(S + off);
                acc[mi][0] = mfma16(a, b0, acc[mi][0]);
                acc[mi][1] = mfma16(a, b1, acc[mi][1]);
            }
        }
    }
    u16* outI = out + (size_t)img * 144 * 64 + ocg * 32;
    float bcA = s_bn[lr],      scA = s_bn[32 + lr], shA = s_bn[64 + lr];
    float bcB = s_bn[16 + lr], scB = s_bn[48 + lr], shB = s_bn[80 + lr];
    #pragma unroll
    for (int mi = 0; mi < 5; ++mi) {
        int t = wv + mi * 8;
        if (t < 36) {
            int quad = t * 4 + lg;                // < 144
            float m0 = -3.4e38f, m1 = -3.4e38f;
            #pragma unroll
            for (int r = 0; r < 4; ++r) {
                m0 = fmaxf(m0, fmaxf(acc[mi][0][r] + bcA, 0.f) * scA + shA);
                m1 = fmaxf(m1, fmaxf(acc[mi][1][r] + bcB, 0.f) * scB + shB);
            }
            outI[quad * 64 + lr]      = f2bf(m0);
            outI[quad * 64 + 16 + lr] = f2bf(m1);
        }
    }
}

// ---------------------------------------------------------------------------
// conv4 MFMA: 64->128, 3x3, 12->10, pool->5 (unchanged from Round 3).
// ---------------------------------------------------------------------------
__global__ __launch_bounds__(256)
void conv4_mfma(const u16* __restrict__ in, const float* __restrict__ wgt,
                const float* __restrict__ cbias,
                const float* __restrict__ bns, const float* __restrict__ bnb,
                const float* __restrict__ bnm, const float* __restrict__ bnv,
                u16* __restrict__ out)
{
    __shared__ __align__(16) unsigned char S[56192];
    u16* s_w4t = (u16*)(S + 18432);
    float* s_bn = (float*)(S + 55808);

    const int tid = threadIdx.x;
    const int ocg = blockIdx.x & 3;
    const int img = blockIdx.x >> 2;

    const u16* inI = in + (size_t)img * 144 * 64;
    for (int g = tid; g < 144 * 8; g += 256) {
        int pos = g >> 3, part = g & 7;
        int off = (pos * 128 + part * 16) ^ ((pos & 7) << 4);
        *(bf16x8*)(S + off) = *(const bf16x8*)(inI + g * 8);
    }
    for (int idx = tid; idx < 32 * 584; idx += 256) {
        int k = idx % 584, oc = idx / 584;
        float v = 0.f;
        if (k < 576) v = wgt[((ocg * 32 + oc) * 64 + (k & 63)) * 9 + (k >> 6)];
        s_w4t[oc * 584 + k] = f2bf(v);
    }
    if (tid < 32) {
        int oc = ocg * 32 + tid;
        float sc = bns[oc] * rsqrtf(bnv[oc] + 1e-5f);
        s_bn[tid] = cbias[oc]; s_bn[32 + tid] = sc; s_bn[64 + tid] = bnb[oc] - bnm[oc] * sc;
    }
    __syncthreads();

    const int w = tid >> 6, lr = tid & 15, lg = (tid >> 4) & 3;
    f32x4 acc[2][2];
    {
        f32x4 z = {0.f, 0.f, 0.f, 0.f};
        acc[0][0] = z; acc[0][1] = z; acc[1][0] = z; acc[1][1] = z;
    }
    int y2a[2], x2a[2];
    #pragma unroll
    for (int mi = 0; mi < 2; ++mi) {
        int aquad = (w + mi * 4) * 4 + (lr >> 2);
        if (aquad > 24) aquad = 24;
        y2a[mi] = 2 * (aquad / 5) + ((lr >> 1) & 1);
        x2a[mi] = 2 * (aquad % 5) + (lr & 1);
    }
    for (int ks = 0; ks < 18; ++ks) {
        int kb2 = (ks * 32 + lg * 8) * 2;
        bf16x8 b0 = *(const bf16x8*)(S + 18432 + lr * 1168 + kb2);
        bf16x8 b1 = *(const bf16x8*)(S + 18432 + (16 + lr) * 1168 + kb2);
        int cell = ks >> 1;
        int ky = cell / 3, kx = cell % 3;
        int icbv = (ks & 1) * 64 + lg * 16;
        #pragma unroll
        for (int mi = 0; mi < 2; ++mi) {
            int pos = (y2a[mi] + ky) * 12 + x2a[mi] + kx;
            int off = (pos * 128 + icbv) ^ ((pos & 7) << 4);
            bf16x8 a = *(const bf16x8*)(S + off);
            acc[mi][0] = mfma16(a, b0, acc[mi][0]);
            acc[mi][1] = mfma16(a, b1, acc[mi][1]);
        }
    }
    u16* outI = out + (size_t)img * 3200;
    float bc0 = s_bn[lr],      sc0 = s_bn[32 + lr], sh0 = s_bn[64 + lr];
    float bc1 = s_bn[16 + lr], sc1 = s_bn[48 + lr], sh1 = s_bn[80 + lr];
    #pragma unroll
    for (int mi = 0; mi < 2; ++mi) {
        int quad = (w + mi * 4) * 4 + lg;
        if (quad < 25) {
            float m0 = -3.4e38f, m1 = -3.4e38f;
            #pragma unroll
            for (int r2 = 0; r2 < 4; ++r2) {
                m0 = fmaxf(m0, fmaxf(acc[mi][0][r2] + bc0, 0.f) * sc0 + sh0);
                m1 = fmaxf(m1, fmaxf(acc[mi][1][r2] + bc1, 0.f) * sc1 + sh1);
            }
            outI[(ocg * 32 + lr) * 25 + quad]      = f2bf(m0);
            outI[(ocg * 32 + 16 + lr) * 25 + quad] = f2bf(m1);
        }
    }
}

// ---------------------------------------------------------------------------
// fc MFMA GEMM (unchanged from Round 3).
// ---------------------------------------------------------------------------
template<bool OUTF32>
__global__ __launch_bounds__(256)
void fc_mfma(const u16* __restrict__ A, const float* __restrict__ Wt,
             const float* __restrict__ bias, void* __restrict__ outv,
             int M, int N, int K)
{
    __shared__ __align__(16) unsigned char S[10240];
    const int tid = threadIdx.x;
    const int n0 = blockIdx.x * 64, m0 = blockIdx.y * 64;
    const int w = tid >> 6, lr = tid & 15, lg = (tid >> 4) & 3;
    const int srow = tid >> 2, spart = tid & 3;

    f32x4 acc[4];
    {
        f32x4 z = {0.f, 0.f, 0.f, 0.f};
        acc[0] = z; acc[1] = z; acc[2] = z; acc[3] = z;
    }
    for (int k0 = 0; k0 < K; k0 += 32) {
        *(bf16x8*)(S + srow * 80 + spart * 16) =
            *(const bf16x8*)(A + (size_t)(m0 + srow) * K + k0 + spart * 8);
        const float* wsrc = Wt + (size_t)(n0 + srow) * K + k0 + spart * 8;
        bf16x8 bv;
        #pragma unroll
        for (int j = 0; j < 8; ++j) ((u16*)&bv)[j] = f2bf(wsrc[j]);
        *(bf16x8*)(S + 5120 + srow * 80 + spart * 16) = bv;
        __syncthreads();
        bf16x8 af = *(const bf16x8*)(S + (w * 16 + lr) * 80 + lg * 16);
        #pragma unroll
        for (int nt = 0; nt < 4; ++nt) {
            bf16x8 bfr = *(const bf16x8*)(S + 5120 + (nt * 16 + lr) * 80 + lg * 16);
            acc[nt] = mfma16(af, bfr, acc[nt]);
        }
        __syncthreads();
    }
    #pragma unroll
    for (int nt = 0; nt < 4; ++nt) {
        int col = n0 + nt * 16 + lr;
        float bv = bias[col];
        #pragma unroll
        for (int r2 = 0; r2 < 4; ++r2) {
            int row = m0 + w * 16 + lg * 4 + r2;
            float v = fmaxf(acc[nt][r2] + bv, 0.f);
            if (OUTF32) ((float*)outv)[(size_t)row * N + col] = v;
            else        ((u16*)outv)[(size_t)row * N + col] = f2bf(v);
        }
    }
}

// ---------------------------------------------------------------------------
__global__ __launch_bounds__(64)
void fc3_sigmoid(const float* __restrict__ A, const float* __restrict__ W,
                 const float* __restrict__ bias, float* __restrict__ out)
{
    __shared__ float4 sa[128];
    const int img = blockIdx.x, t = threadIdx.x;
    const float4* Ar = (const float4*)(A + (size_t)img * 512);
    sa[t] = Ar[t]; sa[t + 64] = Ar[t + 64];
    __syncthreads();
    if (t < 37) {
        const float4* w4 = (const float4*)(W + (size_t)t * 512);
        float s = bias[t];
        #pragma unroll 4
        for (int k = 0; k < 128; ++k) {
            float4 a = sa[k], ww = w4[k];
            s = fmaf(a.x, ww.x, s); s = fmaf(a.y, ww.y, s);
            s = fmaf(a.z, ww.z, s); s = fmaf(a.w, ww.w, s);
        }
        out[(size_t)img * 37 + t] = 1.f / (1.f + expf(-s));
    }
}

// ---------------------------------------------------------------------------
__global__ __launch_bounds__(256)
void norm_mult(float* __restrict__ io)
{
    const int row = blockIdx.x * blockDim.x + threadIdx.x;
    if (row >= BATCH) return;
    float* p = io + (size_t)row * 37;
    float x[37];
    #pragma unroll
    for (int i = 0; i < 37; ++i) x[i] = p[i];
    const int ss[11]  = {0, 3, 5, 7, 9, 13, 15, 18, 25, 28, 31};
    const int ee[11]  = {3, 5, 7, 9, 13, 15, 18, 25, 28, 31, 37};
    const int dep[11] = {-1, 1, 4, 4, 4, -1, 0, 13, 3, 7, 7};
    #pragma unroll
    for (int i = 0; i < 11; ++i) {
        for (int j = ss[i]; j < ee[i]; ++j) {
            float ssum = 0.f;
            for (int c = ss[i]; c < ee[i]; ++c) ssum += x[c];
            x[j] = x[j] / (ssum + 1e-12f);
        }
    }
    #pragma unroll
    for (int i = 0; i < 11; ++i) {
        if (dep[i] >= 0) {
            const float m = x[dep[i]];
            for (int c = ss[i]; c < ee[i]; ++c) x[c] *= m;
        }
    }
    #pragma unroll
    for (int i = 0; i < 37; ++i) p[i] = x[i];
}

// ---------------------------------------------------------------------------
extern "C" void kernel_launch(void* const* d_in, const int* in_sizes, int n_in,
                              void* d_out, int out_size, void* d_ws, size_t ws_size,
                              hipStream_t stream)
{
    const float* x   = (const float*)d_in[0];
    const float* c1w = (const float*)d_in[1];  const float* c1b = (const float*)d_in[2];
    const float* b1s = (const float*)d_in[3];  const float* b1b = (const float*)d_in[4];
    const float* b1m = (const float*)d_in[5];  const float* b1v = (const float*)d_in[6];
    const float* c2w = (const float*)d_in[7];  const float* c2b = (const float*)d_in[8];
    const float* b2s = (const float*)d_in[9];  const float* b2b = (const float*)d_in[10];
    const float* b2m = (const float*)d_in[11]; const float* b2v = (const float*)d_in[12];
    const float* c3w = (const float*)d_in[13]; const float* c3b = (const float*)d_in[14];
    const float* b3s = (const float*)d_in[15]; const float* b3b = (const float*)d_in[16];
    const float* b3m = (const float*)d_in[17]; const float* b3v = (const float*)d_in[18];
    const float* c4w = (const float*)d_in[19]; const float* c4b = (const float*)d_in[20];
    const float* b4s = (const float*)d_in[21]; const float* b4b = (const float*)d_in[22];
    const float* b4m = (const float*)d_in[23]; const float* b4v = (const float*)d_in[24];
    const float* f1w = (const float*)d_in[25]; const float* f1b = (const float*)d_in[26];
    const float* f2w = (const float*)d_in[27]; const float* f2b = (const float*)d_in[28];
    const float* f3w = (const float*)d_in[29]; const float* f3b = (const float*)d_in[30];

    // Workspace (bytes), peak 73.9 MB (same layout as Round 3):
    u16*   P2 = (u16*)d_ws;
    u16*   P3 = (u16*)((char*)d_ws + 44302336);
    u16*   P4 = (u16*)((char*)d_ws + 63176704);
    u16*   F1 = (u16*)((char*)d_ws + 69730304);
    float* F2 = (float*)((char*)d_ws + 71827456);

    conv12_fused<<<BATCH * 4, 512, 0, stream>>>(x, c1w, c1b, b1s, b1b, b1m, b1v,
                                                c2w, c2b, b2s, b2b, b2m, b2v, P2);
    conv3_mfma<<<BATCH * 2, 512, 0, stream>>>(P2, c3w, c3b, b3s, b3b, b3m, b3v, P3);
    conv4_mfma<<<BATCH * 4, 256, 0, stream>>>(P3, c4w, c4b, b4s, b4b, b4m, b4v, P4);

    fc_mfma<false><<<dim3(16, 16), 256, 0, stream>>>(P4, f1w, f1b, F1, 1024, 1024, 3200);
    fc_mfma<true ><<<dim3(8, 16),  256, 0, stream>>>(F1, f2w, f2b, F2, 1024, 512, 1024);
    fc3_sigmoid<<<BATCH, 64, 0, stream>>>(F2, f3w, f3b, (float*)d_out);
    norm_mult<<<(BATCH + 255) / 256, 256, 0, stream>>>((float*)d_out);
}

// Round 6
// 398.100 us; speedup vs baseline: 8.8535x; 1.0483x over previous
//
#include <hip/hip_runtime.h>
#include <hip/hip_bf16.h>
#include <math.h>

constexpr int BATCH = 1024;
typedef unsigned short u16;
typedef unsigned long long u64;
typedef __attribute__((ext_vector_type(8))) short bf16x8;
typedef __attribute__((ext_vector_type(4))) float f32x4;

__device__ __forceinline__ u16 f2bf(float f) {
    union { __hip_bfloat16 b; u16 s; } u; u.b = __float2bfloat16(f); return u.s;
}
__device__ __forceinline__ f32x4 mfma16(bf16x8 a, bf16x8 b, f32x4 c) {
    return __builtin_amdgcn_mfma_f32_16x16x32_bf16(a, b, c, 0, 0, 0);
}

// ---------------------------------------------------------------------------
// Fused conv1(3->16, MFMA) + bn1 + conv2(16->32, MFMA) + bn2 + pool.
// Block = (img, quadrant), 512 threads = 8 waves.
// s_c1: [900 pos][16 ic bf16 = 32B data + 8B pad] pitch 40B  -> banks
//   10*pos mod 32, gcd(10,32)=2 => <=2-way conflicts (free), NO XOR swizzle.
// conv2 A-read addressing: pbase[mi] (reg) + dp (const after unroll) = 1 add.
// LDS: s_c1 36000 | union{s_x 9248 + s_w1 4096 , s_w2t 27136} | bn 576
//    = 63,712 B -> 2 blocks/CU.
// ---------------------------------------------------------------------------
__global__ __launch_bounds__(512, 4)
void conv12_fused(const float* __restrict__ x,
                  const float* __restrict__ c1w, const float* __restrict__ c1b,
                  const float* __restrict__ b1s, const float* __restrict__ b1b,
                  const float* __restrict__ b1m, const float* __restrict__ b1v,
                  const float* __restrict__ c2w, const float* __restrict__ c2b,
                  const float* __restrict__ b2s, const float* __restrict__ b2b,
                  const float* __restrict__ b2m, const float* __restrict__ b2v,
                  u16* __restrict__ out)
{
    __shared__ __align__(16) unsigned char S[63712];
    constexpr int U = 36000;                  // union region base
    float* s_bn1 = (float*)(S + 63136);       // [48]
    float* s_bn2 = (float*)(S + 63328);       // [96]

    const int tid = threadIdx.x;
    int bid = blockIdx.x;
    const int qx = bid & 1, qy = (bid >> 1) & 1, img = bid >> 2;

    // ---- phase 0: stage x-tile (f32->bf16 ic-minor), conv1 weights, bn ----
    const float* xI = x + (size_t)img * 10800 + (qy * 26) * 60 + qx * 26;
    for (int i = tid; i < 34 * 34; i += 512) {
        int yy = i / 34, xx = i - yy * 34;
        const float* p = xI + yy * 60 + xx;
        u16 pk[4];
        pk[0] = f2bf(p[0]); pk[1] = f2bf(p[3600]); pk[2] = f2bf(p[7200]); pk[3] = 0;
        *(u64*)(S + U + i * 8) = *(u64*)pk;
    }
    for (int i = tid; i < 256; i += 512) {    // s_w1 [16 oc][128 k], k=tap*4+ic
        int oc = i >> 4, g = i & 15;
        u16 t8[8];
        #pragma unroll
        for (int j = 0; j < 8; ++j) {
            int k = g * 8 + j, tap = k >> 2, ic = k & 3;
            t8[j] = (ic < 3 && tap < 25) ? f2bf(c1w[oc * 75 + ic * 25 + tap]) : (u16)0;
        }
        *(bf16x8*)(S + U + 9248 + oc * 256 + g * 16) = *(bf16x8*)t8;
    }
    if (tid < 16) {
        float sc = b1s[tid] * rsqrtf(b1v[tid] + 1e-5f);
        s_bn1[tid] = c1b[tid]; s_bn1[16 + tid] = sc; s_bn1[32 + tid] = b1b[tid] - b1m[tid] * sc;
    } else if (tid >= 32 && tid < 64) {
        int t = tid - 32;
        float sc = b2s[t] * rsqrtf(b2v[t] + 1e-5f);
        s_bn2[t] = c2b[t]; s_bn2[32 + t] = sc; s_bn2[64 + t] = b2b[t] - b2m[t] * sc;
    }
    __syncthreads();

    const int wv = tid >> 6, lr = tid & 15, lg = (tid >> 4) & 3;

    // ---- conv1 via MFMA -> s_c1 (pitch-40 channels-last bf16) ----
    {
        int toff[4][2];
        #pragma unroll
        for (int ks = 0; ks < 4; ++ks)
            #pragma unroll
            for (int h = 0; h < 2; ++h) {
                int t = ks * 8 + lg * 2 + h; if (t > 24) t = 24;
                int ky = t / 5;
                toff[ks][h] = (ky * 34 + (t - ky * 5)) * 8;
            }
        bf16x8 wb[4];
        #pragma unroll
        for (int ks = 0; ks < 4; ++ks)
            wb[ks] = *(const bf16x8*)(S + U + 9248 + lr * 256 + ks * 64 + lg * 16);
        float bc = s_bn1[lr], sc = s_bn1[16 + lr], sh = s_bn1[32 + lr];
        #pragma unroll
        for (int mi = 0; mi < 8; ++mi) {
            int t = wv + mi * 8;
            if (t < 57) {
                int pos = t * 16 + lr; if (pos > 899) pos = 899;
                int py = pos / 30;
                int pb = (py * 34 + (pos - py * 30)) * 8;
                f32x4 a = {0.f, 0.f, 0.f, 0.f};
                #pragma unroll
                for (int ks = 0; ks < 4; ++ks) {
                    union { u64 v[2]; bf16x8 f; } af;
                    af.v[0] = *(const u64*)(S + U + pb + toff[ks][0]);
                    af.v[1] = *(const u64*)(S + U + pb + toff[ks][1]);
                    a = mfma16(af.f, wb[ks], a);
                }
                int wb40 = (t * 16 + lg * 4) * 40 + lr * 2;
                int pw0 = t * 16 + lg * 4;
                #pragma unroll
                for (int r = 0; r < 4; ++r) {
                    if (pw0 + r < 900) {
                        float v = fmaxf(a[r] + bc, 0.f) * sc + sh;
                        *(u16*)(S + wb40 + r * 40) = f2bf(v);
                    }
                }
            }
        }
    }
    __syncthreads();

    // ---- stage conv2 weights over the union region: [32 oc][424 k] ----
    for (int i = tid; i < 32 * 53; i += 512) {
        int oc = i / 53, g = i - (i / 53) * 53;
        u16 t8[8];
        #pragma unroll
        for (int j = 0; j < 8; ++j) {
            int k = g * 8 + j;
            t8[j] = (k < 400) ? f2bf(c2w[oc * 400 + (k & 15) * 25 + (k >> 4)]) : (u16)0;
        }
        *(bf16x8*)(S + U + oc * 848 + g * 16) = *(bf16x8*)t8;
    }
    __syncthreads();

    // ---- conv2 via MFMA: 43 M-tiles, NT=6 per wave ----
    f32x4 acc[6][2];
    #pragma unroll
    for (int mi = 0; mi < 6; ++mi) { f32x4 z = {0.f,0.f,0.f,0.f}; acc[mi][0] = z; acc[mi][1] = z; }
    int pb40[6];
    #pragma unroll
    for (int mi = 0; mi < 6; ++mi) {
        int t = wv + mi * 8; if (t > 42) t = 42;
        int aq = t * 4 + (lr >> 2); if (aq > 168) aq = 168;
        int pyq = aq / 13;
        int y2 = 2 * pyq + ((lr >> 1) & 1);
        int x2 = 2 * (aq - pyq * 13) + (lr & 1);
        pb40[mi] = (y2 * 30 + x2) * 40 + (lg & 1) * 16;
    }
    const int csel = lg >> 1;
    #pragma unroll
    for (int ks = 0; ks < 13; ++ks) {
        bf16x8 b0 = *(const bf16x8*)(S + U + lr * 848 + ks * 64 + lg * 16);
        bf16x8 b1 = *(const bf16x8*)(S + U + (16 + lr) * 848 + ks * 64 + lg * 16);
        const int c0 = ks * 2;
        const int c1 = (ks * 2 + 1 > 24) ? 24 : ks * 2 + 1;
        const int dpA = ((c0 / 5) * 30 + (c0 % 5)) * 40;
        const int dpB = ((c1 / 5) * 30 + (c1 % 5)) * 40;
        int dp = csel ? dpB : dpA;
        #pragma unroll
        for (int mi = 0; mi < 6; ++mi) {
            int t = wv + mi * 8;
            if (t < 43) {
                int ad = pb40[mi] + dp;
                union { u64 v[2]; bf16x8 f; } af;
                af.v[0] = *(const u64*)(S + ad);
                af.v[1] = *(const u64*)(S + ad + 8);
                acc[mi][0] = mfma16(af.f, b0, acc[mi][0]);
                acc[mi][1] = mfma16(af.f, b1, acc[mi][1]);
            }
        }
    }
    // ---- epilogue: bias -> relu -> bn -> in-lane 2x2 pool -> global ----
    u16* outI = out + (size_t)img * 676 * 32;
    float bcA = s_bn2[lr],      scA = s_bn2[32 + lr], shA = s_bn2[64 + lr];
    float bcB = s_bn2[16 + lr], scB = s_bn2[48 + lr], shB = s_bn2[80 + lr];
    #pragma unroll
    for (int mi = 0; mi < 6; ++mi) {
        int t = wv + mi * 8;
        if (t < 43) {
            int quad = t * 4 + lg;
            if (quad < 169) {
                int py = quad / 13, px = quad - (quad / 13) * 13;
                int gpos = (qy * 13 + py) * 26 + qx * 13 + px;
                float m0 = -3.4e38f, m1 = -3.4e38f;
                #pragma unroll
                for (int r = 0; r < 4; ++r) {
                    m0 = fmaxf(m0, fmaxf(acc[mi][0][r] + bcA, 0.f) * scA + shA);
                    m1 = fmaxf(m1, fmaxf(acc[mi][1][r] + bcB, 0.f) * scB + shB);
                }
                outI[gpos * 32 + lr]      = f2bf(m0);
                outI[gpos * 32 + 16 + lr] = f2bf(m1);
            }
        }
    }
}

// ---------------------------------------------------------------------------
// conv3 MFMA: 32->64, 3x3, 26->24, pool->12. Block=(img, oc-half), 512 thr.
// XOR layout kept; addressing folded: pa = pb6[mi]+dp6(const), swz=(pa>>3)&0x70.
// ---------------------------------------------------------------------------
__global__ __launch_bounds__(512, 4)
void conv3_mfma(const u16* __restrict__ in, const float* __restrict__ wgt,
                const float* __restrict__ cbias,
                const float* __restrict__ bns, const float* __restrict__ bnb,
                const float* __restrict__ bnm, const float* __restrict__ bnv,
                u16* __restrict__ out)
{
    __shared__ __align__(16) unsigned char S[62592];
    float* s_bn = (float*)(S + 62208);

    const int tid = threadIdx.x;
    const int ocg = blockIdx.x & 1;
    const int img = blockIdx.x >> 1;

    const u16* inI = in + (size_t)img * 676 * 32;
    for (int g = tid; g < 676 * 4; g += 512) {
        int pos = g >> 2, part = g & 3;
        int off = (pos * 64 + part * 16) ^ (((pos >> 1) & 7) << 4);
        *(bf16x8*)(S + off) = *(const bf16x8*)(inI + g * 8);
    }
    for (int i = tid; i < 32 * 37; i += 512) {    // w3t [32][296], k=cell*32+ic
        int oc = i / 37, g = i - (i / 37) * 37;
        u16 t8[8];
        #pragma unroll
        for (int j = 0; j < 8; ++j) {
            int k = g * 8 + j;
            t8[j] = (k < 288) ? f2bf(wgt[((ocg * 32 + oc) * 32 + (k & 31)) * 9 + (k >> 5)]) : (u16)0;
        }
        *(bf16x8*)(S + 43264 + oc * 592 + g * 16) = *(bf16x8*)t8;
    }
    if (tid < 32) {
        int oc = ocg * 32 + tid;
        float sc = bns[oc] * rsqrtf(bnv[oc] + 1e-5f);
        s_bn[tid] = cbias[oc]; s_bn[32 + tid] = sc; s_bn[64 + tid] = bnb[oc] - bnm[oc] * sc;
    }
    __syncthreads();

    const int wv = tid >> 6, lr = tid & 15, lg = (tid >> 4) & 3;
    f32x4 acc[5][2];
    #pragma unroll
    for (int mi = 0; mi < 5; ++mi) { f32x4 z = {0.f,0.f,0.f,0.f}; acc[mi][0] = z; acc[mi][1] = z; }
    int pb6[5];
    #pragma unroll
    for (int mi = 0; mi < 5; ++mi) {
        int t = wv + mi * 8; if (t > 35) t = 35;
        int aq = t * 4 + (lr >> 2);               // < 144
        int pyq = aq / 12;
        int y2 = 2 * pyq + ((lr >> 1) & 1);
        int x2 = 2 * (aq - pyq * 12) + (lr & 1);
        pb6[mi] = ((y2 * 26 + x2) << 6) + lg * 16;
    }
    #pragma unroll
    for (int ks = 0; ks < 9; ++ks) {
        bf16x8 b0 = *(const bf16x8*)(S + 43264 + lr * 592 + ks * 64 + lg * 16);
        bf16x8 b1 = *(const bf16x8*)(S + 43264 + (16 + lr) * 592 + ks * 64 + lg * 16);
        const int dp6 = ((ks / 3) * 26 + (ks % 3)) << 6;
        #pragma unroll
        for (int mi = 0; mi < 5; ++mi) {
            int t = wv + mi * 8;
            if (t < 36) {
                int pa = pb6[mi] + dp6;
                int off = pa ^ ((pa >> 3) & 0x70);
                bf16x8 a = *(const bf16x8*)(S + off);
                acc[mi][0] = mfma16(a, b0, acc[mi][0]);
                acc[mi][1] = mfma16(a, b1, acc[mi][1]);
            }
        }
    }
    u16* outI = out + (size_t)img * 144 * 64 + ocg * 32;
    float bcA = s_bn[lr],      scA = s_bn[32 + lr], shA = s_bn[64 + lr];
    float bcB = s_bn[16 + lr], scB = s_bn[48 + lr], shB = s_bn[80 + lr];
    #pragma unroll
    for (int mi = 0; mi < 5; ++mi) {
        int t = wv + mi * 8;
        if (t < 36) {
            int quad = t * 4 + lg;                // < 144
            float m0 = -3.4e38f, m1 = -3.4e38f;
            #pragma unroll
            for (int r = 0; r < 4; ++r) {
                m0 = fmaxf(m0, fmaxf(acc[mi][0][r] + bcA, 0.f) * scA + shA);
                m1 = fmaxf(m1, fmaxf(acc[mi][1][r] + bcB, 0.f) * scB + shB);
            }
            outI[quad * 64 + lr]      = f2bf(m0);
            outI[quad * 64 + 16 + lr] = f2bf(m1);
        }
    }
}

// ---------------------------------------------------------------------------
// conv4 MFMA: 64->128, 3x3, 12->10, pool->5. Same folded addressing.
// ---------------------------------------------------------------------------
__global__ __launch_bounds__(256)
void conv4_mfma(const u16* __restrict__ in, const float* __restrict__ wgt,
                const float* __restrict__ cbias,
                const float* __restrict__ bns, const float* __restrict__ bnb,
                const float* __restrict__ bnm, const float* __restrict__ bnv,
                u16* __restrict__ out)
{
    __shared__ __align__(16) unsigned char S[56192];
    u16* s_w4t = (u16*)(S + 18432);
    float* s_bn = (float*)(S + 55808);

    const int tid = threadIdx.x;
    const int ocg = blockIdx.x & 3;
    const int img = blockIdx.x >> 2;

    const u16* inI = in + (size_t)img * 144 * 64;
    for (int g = tid; g < 144 * 8; g += 256) {
        int pos = g >> 3, part = g & 7;
        int off = (pos * 128 + part * 16) ^ ((pos & 7) << 4);
        *(bf16x8*)(S + off) = *(const bf16x8*)(inI + g * 8);
    }
    for (int idx = tid; idx < 32 * 584; idx += 256) {
        int k = idx % 584, oc = idx / 584;
        float v = 0.f;
        if (k < 576) v = wgt[((ocg * 32 + oc) * 64 + (k & 63)) * 9 + (k >> 6)];
        s_w4t[oc * 584 + k] = f2bf(v);
    }
    if (tid < 32) {
        int oc = ocg * 32 + tid;
        float sc = bns[oc] * rsqrtf(bnv[oc] + 1e-5f);
        s_bn[tid] = cbias[oc]; s_bn[32 + tid] = sc; s_bn[64 + tid] = bnb[oc] - bnm[oc] * sc;
    }
    __syncthreads();

    const int w = tid >> 6, lr = tid & 15, lg = (tid >> 4) & 3;
    f32x4 acc[2][2];
    {
        f32x4 z = {0.f, 0.f, 0.f, 0.f};
        acc[0][0] = z; acc[0][1] = z; acc[1][0] = z; acc[1][1] = z;
    }
    int pb7[2];
    #pragma unroll
    for (int mi = 0; mi < 2; ++mi) {
        int aq = (w + mi * 4) * 4 + (lr >> 2);
        if (aq > 24) aq = 24;
        int y2 = 2 * (aq / 5) + ((lr >> 1) & 1);
        int x2 = 2 * (aq % 5) + (lr & 1);
        pb7[mi] = ((y2 * 12 + x2) << 7) + lg * 16;
    }
    #pragma unroll
    for (int ks = 0; ks < 18; ++ks) {
        bf16x8 b0 = *(const bf16x8*)(S + 18432 + lr * 1168 + ks * 64 + lg * 16);
        bf16x8 b1 = *(const bf16x8*)(S + 18432 + (16 + lr) * 1168 + ks * 64 + lg * 16);
        const int cell = ks >> 1;
        const int dp7 = (((cell / 3) * 12 + (cell % 3)) << 7) + (ks & 1) * 64;
        #pragma unroll
        for (int mi = 0; mi < 2; ++mi) {
            int pa = pb7[mi] + dp7;
            int off = pa ^ ((pa >> 3) & 0x70);
            bf16x8 a = *(const bf16x8*)(S + off);
            acc[mi][0] = mfma16(a, b0, acc[mi][0]);
            acc[mi][1] = mfma16(a, b1, acc[mi][1]);
        }
    }
    u16* outI = out + (size_t)img * 3200;
    float bc0 = s_bn[lr],      sc0 = s_bn[32 + lr], sh0 = s_bn[64 + lr];
    float bc1 = s_bn[16 + lr], sc1 = s_bn[48 + lr], sh1 = s_bn[80 + lr];
    #pragma unroll
    for (int mi = 0; mi < 2; ++mi) {
        int quad = (w + mi * 4) * 4 + lg;
        if (quad < 25) {
            float m0 = -3.4e38f, m1 = -3.4e38f;
            #pragma unroll
            for (int r2 = 0; r2 < 4; ++r2) {
                m0 = fmaxf(m0, fmaxf(acc[mi][0][r2] + bc0, 0.f) * sc0 + sh0);
                m1 = fmaxf(m1, fmaxf(acc[mi][1][r2] + bc1, 0.f) * sc1 + sh1);
            }
            outI[(ocg * 32 + lr) * 25 + quad]      = f2bf(m0);
            outI[(ocg * 32 + 16 + lr) * 25 + quad] = f2bf(m1);
        }
    }
}

// ---------------------------------------------------------------------------
// Weight converter: f1w (1024x3200) and f2w (512x1024) f32 -> bf16, one pass.
// ---------------------------------------------------------------------------
__global__ __launch_bounds__(256)
void cvt_w(const float* __restrict__ w1, const float* __restrict__ w2,
           u16* __restrict__ o1, u16* __restrict__ o2)
{
    const int i = blockIdx.x * 256 + threadIdx.x;       // float4 index
    constexpr int N1 = 3276800 / 4;
    if (i < N1) {
        float4 v = ((const float4*)w1)[i];
        u16 p[4] = {f2bf(v.x), f2bf(v.y), f2bf(v.z), f2bf(v.w)};
        *(u64*)(o1 + i * 4) = *(u64*)p;
    } else {
        int j = i - N1;                                  // < 131072
        float4 v = ((const float4*)w2)[j];
        u16 p[4] = {f2bf(v.x), f2bf(v.y), f2bf(v.z), f2bf(v.w)};
        *(u64*)(o2 + j * 4) = *(u64*)p;
    }
}

// ---------------------------------------------------------------------------
// fc GEMM, both operands bf16: out = relu(A[M][K] @ W[N][K]^T + bias).
// BM=64, BN=64, BK=128; 256 thr = 4 waves; 16 MFMA per wave per k-iter.
// Staging: thread (r=tid>>2, c=tid&3) loads 4 x bf16x8 per matrix covering
// the FULL 256B row: byte c*16 + q*64  <->  k = c*8 + q*32, q=0..3.
// LDS pitch 272 B (2-way-free bank spread).
// ---------------------------------------------------------------------------
template<bool OUTF32>
__global__ __launch_bounds__(256)
void fc_gemm_bf(const u16* __restrict__ A, const u16* __restrict__ Wb,
                const float* __restrict__ bias, void* __restrict__ outv,
                int M, int N, int K)
{
    __shared__ __align__(16) unsigned char S[34816];   // sA 64x272 | sB 64x272
    const int tid = threadIdx.x;
    const int n0 = blockIdx.x * 64, m0 = blockIdx.y * 64;
    const int w = tid >> 6, lr = tid & 15, lg = (tid >> 4) & 3;
    const int r = tid >> 2, c = tid & 3;

    f32x4 acc[4];
    { f32x4 z = {0.f,0.f,0.f,0.f}; acc[0]=z; acc[1]=z; acc[2]=z; acc[3]=z; }

    const u16* Ab = A  + (size_t)(m0 + r) * K + c * 8;
    const u16* Bb = Wb + (size_t)(n0 + r) * K + c * 8;
    unsigned char* sAw = S + r * 272 + c * 16;
    unsigned char* sBw = S + 17408 + r * 272 + c * 16;

    for (int k0 = 0; k0 < K; k0 += 128) {
        #pragma unroll
        for (int q = 0; q < 4; ++q) {
            *(bf16x8*)(sAw + q * 64) = *(const bf16x8*)(Ab + k0 + q * 32);
            *(bf16x8*)(sBw + q * 64) = *(const bf16x8*)(Bb + k0 + q * 32);
        }
        __syncthreads();
        #pragma unroll
        for (int k32 = 0; k32 < 4; ++k32) {
            bf16x8 a = *(const bf16x8*)(S + (w * 16 + lr) * 272 + k32 * 64 + lg * 16);
            #pragma unroll
            for (int nt = 0; nt < 4; ++nt) {
                bf16x8 b = *(const bf16x8*)(S + 17408 + (nt * 16 + lr) * 272 + k32 * 64 + lg * 16);
                acc[nt] = mfma16(a, b, acc[nt]);
            }
        }
        __syncthreads();
    }
    #pragma unroll
    for (int nt = 0; nt < 4; ++nt) {
        int col = n0 + nt * 16 + lr;
        float bv = bias[col];
        #pragma unroll
        for (int r2 = 0; r2 < 4; ++r2) {
            int row = m0 + w * 16 + lg * 4 + r2;
            float v = fmaxf(acc[nt][r2] + bv, 0.f);
            if (OUTF32) ((float*)outv)[(size_t)row * N + col] = v;
            else        ((u16*)outv)[(size_t)row * N + col] = f2bf(v);
        }
    }
}

// ---------------------------------------------------------------------------
// Fused fc3 (512->37) + sigmoid + sequential normalize + dep-multiply.
// Block = 4 images (4 waves). Lanes 0-36 compute dots; lane 0 runs the exact
// sequential reference recurrence; lanes 0-36 store the row.
// ---------------------------------------------------------------------------
__global__ __launch_bounds__(256)
void fc3_norm(const float* __restrict__ A, const float* __restrict__ W,
              const float* __restrict__ bias, float* __restrict__ out)
{
    __shared__ float sp[4][40];
    const int v = threadIdx.x >> 6, lane = threadIdx.x & 63;
    const int img = blockIdx.x * 4 + v;

    if (lane < 37) {
        const float4* a4 = (const float4*)(A + (size_t)img * 512);
        const float4* w4 = (const float4*)(W + (size_t)lane * 512);
        float s = bias[lane];
        #pragma unroll 4
        for (int k = 0; k < 128; ++k) {
            float4 a = a4[k], ww = w4[k];
            s = fmaf(a.x, ww.x, s); s = fmaf(a.y, ww.y, s);
            s = fmaf(a.z, ww.z, s); s = fmaf(a.w, ww.w, s);
        }
        sp[v][lane] = 1.f / (1.f + expf(-s));
    }
    __syncthreads();
    if (lane == 0) {
        float x[37];
        #pragma unroll
        for (int i = 0; i < 37; ++i) x[i] = sp[v][i];
        const int ss[11]  = {0, 3, 5, 7, 9, 13, 15, 18, 25, 28, 31};
        const int ee[11]  = {3, 5, 7, 9, 13, 15, 18, 25, 28, 31, 37};
        const int dep[11] = {-1, 1, 4, 4, 4, -1, 0, 13, 3, 7, 7};
        #pragma unroll
        for (int i = 0; i < 11; ++i) {
            for (int j = ss[i]; j < ee[i]; ++j) {
                float ssum = 0.f;
                for (int cix = ss[i]; cix < ee[i]; ++cix) ssum += x[cix];
                x[j] = x[j] / (ssum + 1e-12f);
            }
        }
        #pragma unroll
        for (int i = 0; i < 11; ++i) {
            if (dep[i] >= 0) {
                const float m = x[dep[i]];
                for (int cix = ss[i]; cix < ee[i]; ++cix) x[cix] *= m;
            }
        }
        #pragma unroll
        for (int i = 0; i < 37; ++i) sp[v][i] = x[i];
    }
    __syncthreads();
    if (lane < 37) out[(size_t)img * 37 + lane] = sp[v][lane];
}

// ---------------------------------------------------------------------------
extern "C" void kernel_launch(void* const* d_in, const int* in_sizes, int n_in,
                              void* d_out, int out_size, void* d_ws, size_t ws_size,
                              hipStream_t stream)
{
    const float* x   = (const float*)d_in[0];
    const float* c1w = (const float*)d_in[1];  const float* c1b = (const float*)d_in[2];
    const float* b1s = (const float*)d_in[3];  const float* b1b = (const float*)d_in[4];
    const float* b1m = (const float*)d_in[5];  const float* b1v = (const float*)d_in[6];
    const float* c2w = (const float*)d_in[7];  const float* c2b = (const float*)d_in[8];
    const float* b2s = (const float*)d_in[9];  const float* b2b = (const float*)d_in[10];
    const float* b2m = (const float*)d_in[11]; const float* b2v = (const float*)d_in[12];
    const float* c3w = (const float*)d_in[13]; const float* c3b = (const float*)d_in[14];
    const float* b3s = (const float*)d_in[15]; const float* b3b = (const float*)d_in[16];
    const float* b3m = (const float*)d_in[17]; const float* b3v = (const float*)d_in[18];
    const float* c4w = (const float*)d_in[19]; const float* c4b = (const float*)d_in[20];
    const float* b4s = (const float*)d_in[21]; const float* b4b = (const float*)d_in[22];
    const float* b4m = (const float*)d_in[23]; const float* b4v = (const float*)d_in[24];
    const float* f1w = (const float*)d_in[25]; const float* f1b = (const float*)d_in[26];
    const float* f2w = (const float*)d_in[27]; const float* f2b = (const float*)d_in[28];
    const float* f3w = (const float*)d_in[29]; const float* f3b = (const float*)d_in[30];

    // Workspace (bytes), peak 81.5 MB:
    //   P2  bf16 [1024][676][32]  @ 0           44,302,336
    //   P3  bf16 [1024][144][64]  @ 44,302,336  18,874,368
    //   P4  bf16 [1024][3200]     @ 63,176,704   6,553,600
    //   F1  bf16 [1024][1024]     @ 69,730,304   2,097,152
    //   F2  f32  [1024][512]      @ 71,827,456   2,097,152
    //   W1b bf16 [1024][3200]     @ 73,924,608   6,553,600
    //   W2b bf16 [512][1024]      @ 80,478,208   1,048,576
    u16*   P2  = (u16*)d_ws;
    u16*   P3  = (u16*)((char*)d_ws + 44302336);
    u16*   P4  = (u16*)((char*)d_ws + 63176704);
    u16*   F1  = (u16*)((char*)d_ws + 69730304);
    float* F2  = (float*)((char*)d_ws + 71827456);
    u16*   W1b = (u16*)((char*)d_ws + 73924608);
    u16*   W2b = (u16*)((char*)d_ws + 80478208);

    cvt_w<<<(819200 + 131072) / 256, 256, 0, stream>>>(f1w, f2w, W1b, W2b);

    conv12_fused<<<BATCH * 4, 512, 0, stream>>>(x, c1w, c1b, b1s, b1b, b1m, b1v,
                                                c2w, c2b, b2s, b2b, b2m, b2v, P2);
    conv3_mfma<<<BATCH * 2, 512, 0, stream>>>(P2, c3w, c3b, b3s, b3b, b3m, b3v, P3);
    conv4_mfma<<<BATCH * 4, 256, 0, stream>>>(P3, c4w, c4b, b4s, b4b, b4m, b4v, P4);

    fc_gemm_bf<false><<<dim3(16, 16), 256, 0, stream>>>(P4, W1b, f1b, F1, 1024, 1024, 3200);
    fc_gemm_bf<true ><<<dim3(8, 16),  256, 0, stream>>>(F1, W2b, f2b, F2, 1024, 512, 1024);
    fc3_norm<<<BATCH / 4, 256, 0, stream>>>(F2, f3w, f3b, (float*)d_out);
}

// Round 7
// 382.629 us; speedup vs baseline: 9.2115x; 1.0404x over previous
//
#include <hip/hip_runtime.h>
#include <hip/hip_bf16.h>
#include <math.h>

constexpr int BATCH = 1024;
typedef unsigned short u16;
typedef unsigned long long u64;
typedef __attribute__((ext_vector_type(8))) short bf16x8;
typedef __attribute__((ext_vector_type(4))) float f32x4;
typedef __attribute__((ext_vector_type(16))) float f32x16;

__device__ __forceinline__ u16 f2bf(float f) {
    union { __hip_bfloat16 b; u16 s; } u; u.b = __float2bfloat16(f); return u.s;
}
__device__ __forceinline__ f32x4 mfma16(bf16x8 a, bf16x8 b, f32x4 c) {
    return __builtin_amdgcn_mfma_f32_16x16x32_bf16(a, b, c, 0, 0, 0);
}
__device__ __forceinline__ f32x16 mfma32(bf16x8 a, bf16x8 b, f32x16 c) {
    return __builtin_amdgcn_mfma_f32_32x32x16_bf16(a, b, c, 0, 0, 0);
}

// ---------------------------------------------------------------------------
// Fused conv1(3->16, 16x16x32 MFMA) + bn1 + conv2(16->32, 32x32x16 MFMA) +
// bn2 + pool.  Block = (img, quadrant), 512 threads = 8 waves.
// s_c1: [900 pos][16 ch] pitch 32B, channels-last. conv2 A-reads are
// conflict-free: dword bank = 8*(p%4)+..., quad-major rows cover p%4 uniformly.
// conv1 computes C[oc][pos] (A=weights) so each lane writes 4 consecutive
// channels of one position as a single u64 (conflict-free).
// conv2: M = 676 pre-pool positions quad-major (22 tiles of 32), N = 32 oc,
// K = 400 exact (25 taps x 16 ic), 1 B-read + 3 A-reads + 3 MFMA per tap.
// LDS: s_c1 28800 | union{s_x 9248 + s_w1 4096 , s_w2t 25600} | bn 576
//    = 54,976 B -> 2 blocks/CU.
// ---------------------------------------------------------------------------
__global__ __launch_bounds__(512, 4)
void conv12_fused(const float* __restrict__ x,
                  const float* __restrict__ c1w, const float* __restrict__ c1b,
                  const float* __restrict__ b1s, const float* __restrict__ b1b,
                  const float* __restrict__ b1m, const float* __restrict__ b1v,
                  const float* __restrict__ c2w, const float* __restrict__ c2b,
                  const float* __restrict__ b2s, const float* __restrict__ b2b,
                  const float* __restrict__ b2m, const float* __restrict__ b2v,
                  u16* __restrict__ out)
{
    __shared__ __align__(16) unsigned char S[54976];
    constexpr int U = 28800;                  // union region base
    float* s_bn1 = (float*)(S + 54400);       // [48]
    float* s_bn2 = (float*)(S + 54592);       // [96]

    const int tid = threadIdx.x;
    int bid = blockIdx.x;
    const int qx = bid & 1, qy = (bid >> 1) & 1, img = bid >> 2;

    // ---- phase 0: stage x-tile (f32->bf16 ic-minor), conv1 weights, bn ----
    const float* xI = x + (size_t)img * 10800 + (qy * 26) * 60 + qx * 26;
    for (int i = tid; i < 34 * 34; i += 512) {
        int yy = i / 34, xx = i - yy * 34;
        const float* p = xI + yy * 60 + xx;
        u16 pk[4];
        pk[0] = f2bf(p[0]); pk[1] = f2bf(p[3600]); pk[2] = f2bf(p[7200]); pk[3] = 0;
        *(u64*)(S + U + i * 8) = *(u64*)pk;
    }
    for (int i = tid; i < 256; i += 512) {    // s_w1 [16 oc][128 k], k=tap*4+ic
        int oc = i >> 4, g = i & 15;
        u16 t8[8];
        #pragma unroll
        for (int j = 0; j < 8; ++j) {
            int k = g * 8 + j, tap = k >> 2, ic = k & 3;
            t8[j] = (ic < 3 && tap < 25) ? f2bf(c1w[oc * 75 + ic * 25 + tap]) : (u16)0;
        }
        *(bf16x8*)(S + U + 9248 + oc * 256 + g * 16) = *(bf16x8*)t8;
    }
    if (tid < 16) {
        float sc = b1s[tid] * rsqrtf(b1v[tid] + 1e-5f);
        s_bn1[tid] = c1b[tid]; s_bn1[16 + tid] = sc; s_bn1[32 + tid] = b1b[tid] - b1m[tid] * sc;
    } else if (tid >= 32 && tid < 64) {
        int t = tid - 32;
        float sc = b2s[t] * rsqrtf(b2v[t] + 1e-5f);
        s_bn2[t] = c2b[t]; s_bn2[32 + t] = sc; s_bn2[64 + t] = b2b[t] - b2m[t] * sc;
    }
    __syncthreads();

    const int wv = tid >> 6, lr = tid & 15, lg = (tid >> 4) & 3;
    const int o32 = tid & 31, hi = (tid >> 5) & 1;

    // ---- conv1 via MFMA (A = weights -> C[oc][pos]) -> s_c1 pitch-32 ----
    {
        int toff[4][2];
        #pragma unroll
        for (int ks = 0; ks < 4; ++ks)
            #pragma unroll
            for (int h = 0; h < 2; ++h) {
                int t = ks * 8 + lg * 2 + h; if (t > 24) t = 24;
                int ky = t / 5;
                toff[ks][h] = (ky * 34 + (t - ky * 5)) * 8;
            }
        bf16x8 wb[4];
        #pragma unroll
        for (int ks = 0; ks < 4; ++ks)
            wb[ks] = *(const bf16x8*)(S + U + 9248 + lr * 256 + ks * 64 + lg * 16);
        float4 bnB = *(const float4*)(s_bn1 + lg * 4);        // bias oc=4lg..+3
        float4 bnS = *(const float4*)(s_bn1 + 16 + lg * 4);
        float4 bnH = *(const float4*)(s_bn1 + 32 + lg * 4);
        #pragma unroll
        for (int mi = 0; mi < 8; ++mi) {
            int t = wv + mi * 8;
            if (t < 57) {
                int pos = t * 16 + lr;
                int pc = pos > 899 ? 899 : pos;
                int py = pc / 30;
                int pb = (py * 34 + (pc - py * 30)) * 8;
                f32x4 a = {0.f, 0.f, 0.f, 0.f};
                #pragma unroll
                for (int ks = 0; ks < 4; ++ks) {
                    union { u64 v[2]; bf16x8 f; } xf;
                    xf.v[0] = *(const u64*)(S + U + pb + toff[ks][0]);
                    xf.v[1] = *(const u64*)(S + U + pb + toff[ks][1]);
                    a = mfma16(wb[ks], xf.f, a);   // A=weights, B=x
                }
                if (pos < 900) {
                    u16 q[4];
                    q[0] = f2bf(fmaxf(a[0] + bnB.x, 0.f) * bnS.x + bnH.x);
                    q[1] = f2bf(fmaxf(a[1] + bnB.y, 0.f) * bnS.y + bnH.y);
                    q[2] = f2bf(fmaxf(a[2] + bnB.z, 0.f) * bnS.z + bnH.z);
                    q[3] = f2bf(fmaxf(a[3] + bnB.w, 0.f) * bnS.w + bnH.w);
                    *(u64*)(S + pos * 32 + lg * 8) = *(u64*)q;
                }
            }
        }
    }
    __syncthreads();

    // ---- stage conv2 weights: s_w2t [32 oc][400 k] (k = tap*16+ic), 800B ----
    for (int i = tid; i < 32 * 50; i += 512) {
        int oc = i / 50, g = i - (i / 50) * 50;
        u16 t8[8];
        #pragma unroll
        for (int j = 0; j < 8; ++j) {
            int k = g * 8 + j;
            t8[j] = f2bf(c2w[oc * 400 + (k & 15) * 25 + (k >> 4)]);
        }
        *(bf16x8*)(S + U + oc * 800 + g * 16) = *(bf16x8*)t8;
    }
    __syncthreads();

    // ---- conv2 via 32x32x16 MFMA: 22 M-tiles, NT=3/wave, N=32 in one tile ----
    f32x16 acc[3];
    #pragma unroll
    for (int mi = 0; mi < 3; ++mi)
        #pragma unroll
        for (int j = 0; j < 16; ++j) acc[mi][j] = 0.f;
    int pbase[3];
    #pragma unroll
    for (int mi = 0; mi < 3; ++mi) {
        int tt = wv + mi * 8; if (tt > 21) tt = 21;
        int row = tt * 32 + o32;
        int q = row >> 2; if (q > 168) q = 168;
        int Q = row & 3;
        int y2 = 2 * (q / 13) + (Q >> 1);
        int x2 = 2 * (q - (q / 13) * 13) + (Q & 1);
        pbase[mi] = (y2 * 30 + x2) * 32 + hi * 16;
    }
    const unsigned char* wrow = S + U + o32 * 800 + hi * 16;
    #pragma unroll
    for (int ks = 0; ks < 25; ++ks) {
        bf16x8 b = *(const bf16x8*)(wrow + ks * 32);
        const int dp = ((ks / 5) * 30 + (ks % 5)) * 32;
        #pragma unroll
        for (int mi = 0; mi < 3; ++mi) {
            bf16x8 a = *(const bf16x8*)(S + pbase[mi] + dp);
            acc[mi] = mfma32(a, b, acc[mi]);
        }
    }
    // ---- epilogue: bias -> relu -> bn -> in-lane 2x2 pool (reg quads) ----
    u16* outI = out + (size_t)img * 676 * 32;
    float bnb = s_bn2[o32], bns = s_bn2[32 + o32], bnh = s_bn2[64 + o32];
    #pragma unroll
    for (int mi = 0; mi < 3; ++mi) {
        int tt = wv + mi * 8;
        if (tt < 22) {
            #pragma unroll
            for (int rg = 0; rg < 4; ++rg) {
                int quad = tt * 8 + 2 * rg + hi;
                if (quad < 169) {
                    float m = -3.4e38f;
                    #pragma unroll
                    for (int r = 0; r < 4; ++r)
                        m = fmaxf(m, fmaxf(acc[mi][rg * 4 + r] + bnb, 0.f) * bns + bnh);
                    int py = quad / 13, px = quad - (quad / 13) * 13;
                    int gpos = (qy * 13 + py) * 26 + qx * 13 + px;
                    outI[gpos * 32 + o32] = f2bf(m);
                }
            }
        }
    }
}

// ---------------------------------------------------------------------------
// conv3 via 32x32x16: 32->64, 3x3, 26->24, pool->12. Block=(img, oc-half),
// 576 threads = 9 waves, 18 M-tiles -> exactly 2 per wave.
// s_in [676 pos][32 ic] pitch 64B with one XOR bit (pa ^ ((pa>>2)&0x20)) ->
// conflict-free reads; w3t [32 oc][304 k] pitch 608B (dword 152 = 24 mod 32).
// LDS: 43264 + 19456 + 384 = 63,104 B -> 2 blocks/CU (18 waves).
// ---------------------------------------------------------------------------
__global__ __launch_bounds__(576, 2)
void conv3_mfma(const u16* __restrict__ in, const float* __restrict__ wgt,
                const float* __restrict__ cbias,
                const float* __restrict__ bns, const float* __restrict__ bnb,
                const float* __restrict__ bnm, const float* __restrict__ bnv,
                u16* __restrict__ out)
{
    __shared__ __align__(16) unsigned char S[63104];
    float* s_bn = (float*)(S + 62720);

    const int tid = threadIdx.x;
    const int ocg = blockIdx.x & 1;
    const int img = blockIdx.x >> 1;

    const u16* inI = in + (size_t)img * 676 * 32;
    for (int g = tid; g < 2704; g += 576) {
        int pa = g * 16;                        // pos*64 + part*16
        int off = pa ^ ((pa >> 2) & 0x20);
        *(bf16x8*)(S + off) = *(const bf16x8*)(inI + g * 8);
    }
    for (int i = tid; i < 32 * 38; i += 576) {  // w3t [32][304], k=cell*32+ic
        int oc = i / 38, g = i - (i / 38) * 38;
        u16 t8[8];
        #pragma unroll
        for (int j = 0; j < 8; ++j) {
            int k = g * 8 + j;
            t8[j] = (k < 288) ? f2bf(wgt[((ocg * 32 + oc) * 32 + (k & 31)) * 9 + (k >> 5)]) : (u16)0;
        }
        *(bf16x8*)(S + 43264 + oc * 608 + g * 16) = *(bf16x8*)t8;
    }
    if (tid < 32) {
        int oc = ocg * 32 + tid;
        float sc = bns[oc] * rsqrtf(bnv[oc] + 1e-5f);
        s_bn[tid] = cbias[oc]; s_bn[32 + tid] = sc; s_bn[64 + tid] = bnb[oc] - bnm[oc] * sc;
    }
    __syncthreads();

    const int wv = tid >> 6;                    // 0..8
    const int o32 = tid & 31, hi = (tid >> 5) & 1;
    f32x16 acc[2];
    #pragma unroll
    for (int mi = 0; mi < 2; ++mi)
        #pragma unroll
        for (int j = 0; j < 16; ++j) acc[mi][j] = 0.f;
    int pbase[2];
    #pragma unroll
    for (int mi = 0; mi < 2; ++mi) {
        int tt = wv * 2 + mi;                   // 0..17 exact
        int row = tt * 32 + o32;
        int q = row >> 2, Q = row & 3;          // q < 144
        int y2 = 2 * (q / 12) + (Q >> 1);
        int x2 = 2 * (q - (q / 12) * 12) + (Q & 1);
        pbase[mi] = (y2 * 26 + x2) * 64 + hi * 16;
    }
    const unsigned char* wrow = S + 43264 + o32 * 608 + hi * 16;
    #pragma unroll
    for (int s = 0; s < 18; ++s) {
        bf16x8 b = *(const bf16x8*)(wrow + s * 32);
        const int cell = s >> 1;
        const int dp = ((cell / 3) * 26 + (cell % 3)) * 64 + (s & 1) * 32;
        #pragma unroll
        for (int mi = 0; mi < 2; ++mi) {
            int pa = pbase[mi] + dp;
            bf16x8 a = *(const bf16x8*)(S + (pa ^ ((pa >> 2) & 0x20)));
            acc[mi] = mfma32(a, b, acc[mi]);
        }
    }
    u16* outI = out + (size_t)img * 144 * 64 + ocg * 32;
    float bnbv = s_bn[o32], bnsv = s_bn[32 + o32], bnhv = s_bn[64 + o32];
    #pragma unroll
    for (int mi = 0; mi < 2; ++mi) {
        int tt = wv * 2 + mi;
        #pragma unroll
        for (int rg = 0; rg < 4; ++rg) {
            int quad = tt * 8 + 2 * rg + hi;    // < 144
            float m = -3.4e38f;
            #pragma unroll
            for (int r = 0; r < 4; ++r)
                m = fmaxf(m, fmaxf(acc[mi][rg * 4 + r] + bnbv, 0.f) * bnsv + bnhv);
            outI[quad * 64 + o32] = f2bf(m);
        }
    }
}

// ---------------------------------------------------------------------------
// conv4 MFMA: 64->128, 3x3, 12->10, pool->5 (unchanged).
// ---------------------------------------------------------------------------
__global__ __launch_bounds__(256)
void conv4_mfma(const u16* __restrict__ in, const float* __restrict__ wgt,
                const float* __restrict__ cbias,
                const float* __restrict__ bns, const float* __restrict__ bnb,
                const float* __restrict__ bnm, const float* __restrict__ bnv,
                u16* __restrict__ out)
{
    __shared__ __align__(16) unsigned char S[56192];
    u16* s_w4t = (u16*)(S + 18432);
    float* s_bn = (float*)(S + 55808);

    const int tid = threadIdx.x;
    const int ocg = blockIdx.x & 3;
    const int img = blockIdx.x >> 2;

    const u16* inI = in + (size_t)img * 144 * 64;
    for (int g = tid; g < 144 * 8; g += 256) {
        int pos = g >> 3, part = g & 7;
        int off = (pos * 128 + part * 16) ^ ((pos & 7) << 4);
        *(bf16x8*)(S + off) = *(const bf16x8*)(inI + g * 8);
    }
    for (int idx = tid; idx < 32 * 584; idx += 256) {
        int k = idx % 584, oc = idx / 584;
        float v = 0.f;
        if (k < 576) v = wgt[((ocg * 32 + oc) * 64 + (k & 63)) * 9 + (k >> 6)];
        s_w4t[oc * 584 + k] = f2bf(v);
    }
    if (tid < 32) {
        int oc = ocg * 32 + tid;
        float sc = bns[oc] * rsqrtf(bnv[oc] + 1e-5f);
        s_bn[tid] = cbias[oc]; s_bn[32 + tid] = sc; s_bn[64 + tid] = bnb[oc] - bnm[oc] * sc;
    }
    __syncthreads();

    const int w = tid >> 6, lr = tid & 15, lg = (tid >> 4) & 3;
    f32x4 acc[2][2];
    {
        f32x4 z = {0.f, 0.f, 0.f, 0.f};
        acc[0][0] = z; acc[0][1] = z; acc[1][0] = z; acc[1][1] = z;
    }
    int pb7[2];
    #pragma unroll
    for (int mi = 0; mi < 2; ++mi) {
        int aq = (w + mi * 4) * 4 + (lr >> 2);
        if (aq > 24) aq = 24;
        int y2 = 2 * (aq / 5) + ((lr >> 1) & 1);
        int x2 = 2 * (aq % 5) + (lr & 1);
        pb7[mi] = ((y2 * 12 + x2) << 7) + lg * 16;
    }
    #pragma unroll
    for (int ks = 0; ks < 18; ++ks) {
        bf16x8 b0 = *(const bf16x8*)(S + 18432 + lr * 1168 + ks * 64 + lg * 16);
        bf16x8 b1 = *(const bf16x8*)(S + 18432 + (16 + lr) * 1168 + ks * 64 + lg * 16);
        const int cell = ks >> 1;
        const int dp7 = (((cell / 3) * 12 + (cell % 3)) << 7) + (ks & 1) * 64;
        #pragma unroll
        for (int mi = 0; mi < 2; ++mi) {
            int pa = pb7[mi] + dp7;
            int off = pa ^ ((pa >> 3) & 0x70);
            bf16x8 a = *(const bf16x8*)(S + off);
            acc[mi][0] = mfma16(a, b0, acc[mi][0]);
            acc[mi][1] = mfma16(a, b1, acc[mi][1]);
        }
    }
    u16* outI = out + (size_t)img * 3200;
    float bc0 = s_bn[lr],      sc0 = s_bn[32 + lr], sh0 = s_bn[64 + lr];
    float bc1 = s_bn[16 + lr], sc1 = s_bn[48 + lr], sh1 = s_bn[80 + lr];
    #pragma unroll
    for (int mi = 0; mi < 2; ++mi) {
        int quad = (w + mi * 4) * 4 + lg;
        if (quad < 25) {
            float m0 = -3.4e38f, m1 = -3.4e38f;
            #pragma unroll
            for (int r2 = 0; r2 < 4; ++r2) {
                m0 = fmaxf(m0, fmaxf(acc[mi][0][r2] + bc0, 0.f) * sc0 + sh0);
                m1 = fmaxf(m1, fmaxf(acc[mi][1][r2] + bc1, 0.f) * sc1 + sh1);
            }
            outI[(ocg * 32 + lr) * 25 + quad]      = f2bf(m0);
            outI[(ocg * 32 + 16 + lr) * 25 + quad] = f2bf(m1);
        }
    }
}

// ---------------------------------------------------------------------------
// Weight converter: f1w (1024x3200) and f2w (512x1024) f32 -> bf16.
// ---------------------------------------------------------------------------
__global__ __launch_bounds__(256)
void cvt_w(const float* __restrict__ w1, const float* __restrict__ w2,
           u16* __restrict__ o1, u16* __restrict__ o2)
{
    const int i = blockIdx.x * 256 + threadIdx.x;       // float4 index
    constexpr int N1 = 3276800 / 4;
    if (i < N1) {
        float4 v = ((const float4*)w1)[i];
        u16 p[4] = {f2bf(v.x), f2bf(v.y), f2bf(v.z), f2bf(v.w)};
        *(u64*)(o1 + i * 4) = *(u64*)p;
    } else {
        int j = i - N1;                                  // < 131072
        float4 v = ((const float4*)w2)[j];
        u16 p[4] = {f2bf(v.x), f2bf(v.y), f2bf(v.z), f2bf(v.w)};
        *(u64*)(o2 + j * 4) = *(u64*)p;
    }
}

// ---------------------------------------------------------------------------
// fc GEMM, both operands bf16 (unchanged from Round 6).
// ---------------------------------------------------------------------------
template<bool OUTF32>
__global__ __launch_bounds__(256)
void fc_gemm_bf(const u16* __restrict__ A, const u16* __restrict__ Wb,
                const float* __restrict__ bias, void* __restrict__ outv,
                int M, int N, int K)
{
    __shared__ __align__(16) unsigned char S[34816];   // sA 64x272 | sB 64x272
    const int tid = threadIdx.x;
    const int n0 = blockIdx.x * 64, m0 = blockIdx.y * 64;
    const int w = tid >> 6, lr = tid & 15, lg = (tid >> 4) & 3;
    const int r = tid >> 2, c = tid & 3;

    f32x4 acc[4];
    { f32x4 z = {0.f,0.f,0.f,0.f}; acc[0]=z; acc[1]=z; acc[2]=z; acc[3]=z; }

    const u16* Ab = A  + (size_t)(m0 + r) * K + c * 8;
    const u16* Bb = Wb + (size_t)(n0 + r) * K + c * 8;
    unsigned char* sAw = S + r * 272 + c * 16;
    unsigned char* sBw = S + 17408 + r * 272 + c * 16;

    for (int k0 = 0; k0 < K; k0 += 128) {
        #pragma unroll
        for (int q = 0; q < 4; ++q) {
            *(bf16x8*)(sAw + q * 64) = *(const bf16x8*)(Ab + k0 + q * 32);
            *(bf16x8*)(sBw + q * 64) = *(const bf16x8*)(Bb + k0 + q * 32);
        }
        __syncthreads();
        #pragma unroll
        for (int k32 = 0; k32 < 4; ++k32) {
            bf16x8 a = *(const bf16x8*)(S + (w * 16 + lr) * 272 + k32 * 64 + lg * 16);
            #pragma unroll
            for (int nt = 0; nt < 4; ++nt) {
                bf16x8 b = *(const bf16x8*)(S + 17408 + (nt * 16 + lr) * 272 + k32 * 64 + lg * 16);
                acc[nt] = mfma16(a, b, acc[nt]);
            }
        }
        __syncthreads();
    }
    #pragma unroll
    for (int nt = 0; nt < 4; ++nt) {
        int col = n0 + nt * 16 + lr;
        float bv = bias[col];
        #pragma unroll
        for (int r2 = 0; r2 < 4; ++r2) {
            int row = m0 + w * 16 + lg * 4 + r2;
            float v = fmaxf(acc[nt][r2] + bv, 0.f);
            if (OUTF32) ((float*)outv)[(size_t)row * N + col] = v;
            else        ((u16*)outv)[(size_t)row * N + col] = f2bf(v);
        }
    }
}

// ---------------------------------------------------------------------------
// Fused fc3 (512->37) + sigmoid + sequential normalize + dep-multiply.
// ---------------------------------------------------------------------------
__global__ __launch_bounds__(256)
void fc3_norm(const float* __restrict__ A, const float* __restrict__ W,
              const float* __restrict__ bias, float* __restrict__ out)
{
    __shared__ float sp[4][40];
    const int v = threadIdx.x >> 6, lane = threadIdx.x & 63;
    const int img = blockIdx.x * 4 + v;

    if (lane < 37) {
        const float4* a4 = (const float4*)(A + (size_t)img * 512);
        const float4* w4 = (const float4*)(W + (size_t)lane * 512);
        float s = bias[lane];
        #pragma unroll 4
        for (int k = 0; k < 128; ++k) {
            float4 a = a4[k], ww = w4[k];
            s = fmaf(a.x, ww.x, s); s = fmaf(a.y, ww.y, s);
            s = fmaf(a.z, ww.z, s); s = fmaf(a.w, ww.w, s);
        }
        sp[v][lane] = 1.f / (1.f + expf(-s));
    }
    __syncthreads();
    if (lane == 0) {
        float xv[37];
        #pragma unroll
        for (int i = 0; i < 37; ++i) xv[i] = sp[v][i];
        const int ss[11]  = {0, 3, 5, 7, 9, 13, 15, 18, 25, 28, 31};
        const int ee[11]  = {3, 5, 7, 9, 13, 15, 18, 25, 28, 31, 37};
        const int dep[11] = {-1, 1, 4, 4, 4, -1, 0, 13, 3, 7, 7};
        #pragma unroll
        for (int i = 0; i < 11; ++i) {
            for (int j = ss[i]; j < ee[i]; ++j) {
                float ssum = 0.f;
                for (int cix = ss[i]; cix < ee[i]; ++cix) ssum += xv[cix];
                xv[j] = xv[j] / (ssum + 1e-12f);
            }
        }
        #pragma unroll
        for (int i = 0; i < 11; ++i) {
            if (dep[i] >= 0) {
                const float m = xv[dep[i]];
                for (int cix = ss[i]; cix < ee[i]; ++cix) xv[cix] *= m;
            }
        }
        #pragma unroll
        for (int i = 0; i < 37; ++i) sp[v][i] = xv[i];
    }
    __syncthreads();
    if (lane < 37) out[(size_t)img * 37 + lane] = sp[v][lane];
}

// ---------------------------------------------------------------------------
extern "C" void kernel_launch(void* const* d_in, const int* in_sizes, int n_in,
                              void* d_out, int out_size, void* d_ws, size_t ws_size,
                              hipStream_t stream)
{
    const float* x   = (const float*)d_in[0];
    const float* c1w = (const float*)d_in[1];  const float* c1b = (const float*)d_in[2];
    const float* b1s = (const float*)d_in[3];  const float* b1b = (const float*)d_in[4];
    const float* b1m = (const float*)d_in[5];  const float* b1v = (const float*)d_in[6];
    const float* c2w = (const float*)d_in[7];  const float* c2b = (const float*)d_in[8];
    const float* b2s = (const float*)d_in[9];  const float* b2b = (const float*)d_in[10];
    const float* b2m = (const float*)d_in[11]; const float* b2v = (const float*)d_in[12];
    const float* c3w = (const float*)d_in[13]; const float* c3b = (const float*)d_in[14];
    const float* b3s = (const float*)d_in[15]; const float* b3b = (const float*)d_in[16];
    const float* b3m = (const float*)d_in[17]; const float* b3v = (const float*)d_in[18];
    const float* c4w = (const float*)d_in[19]; const float* c4b = (const float*)d_in[20];
    const float* b4s = (const float*)d_in[21]; const float* b4b = (const float*)d_in[22];
    const float* b4m = (const float*)d_in[23]; const float* b4v = (const float*)d_in[24];
    const float* f1w = (const float*)d_in[25]; const float* f1b = (const float*)d_in[26];
    const float* f2w = (const float*)d_in[27]; const float* f2b = (const float*)d_in[28];
    const float* f3w = (const float*)d_in[29]; const float* f3b = (const float*)d_in[30];

    // Workspace (bytes), peak 81.5 MB (unchanged layout):
    u16*   P2  = (u16*)d_ws;
    u16*   P3  = (u16*)((char*)d_ws + 44302336);
    u16*   P4  = (u16*)((char*)d_ws + 63176704);
    u16*   F1  = (u16*)((char*)d_ws + 69730304);
    float* F2  = (float*)((char*)d_ws + 71827456);
    u16*   W1b = (u16*)((char*)d_ws + 73924608);
    u16*   W2b = (u16*)((char*)d_ws + 80478208);

    cvt_w<<<(819200 + 131072) / 256, 256, 0, stream>>>(f1w, f2w, W1b, W2b);

    conv12_fused<<<BATCH * 4, 512, 0, stream>>>(x, c1w, c1b, b1s, b1b, b1m, b1v,
                                                c2w, c2b, b2s, b2b, b2m, b2v, P2);
    conv3_mfma<<<BATCH * 2, 576, 0, stream>>>(P2, c3w, c3b, b3s, b3b, b3m, b3v, P3);
    conv4_mfma<<<BATCH * 4, 256, 0, stream>>>(P3, c4w, c4b, b4s, b4b, b4m, b4v, P4);

    fc_gemm_bf<false><<<dim3(16, 16), 256, 0, stream>>>(P4, W1b, f1b, F1, 1024, 1024, 3200);
    fc_gemm_bf<true ><<<dim3(8, 16),  256, 0, stream>>>(F1, W2b, f2b, F2, 1024, 512, 1024);
    fc3_norm<<<BATCH / 4, 256, 0, stream>>>(F2, f3w, f3b, (float*)d_out);
}

// Round 8
// 268.539 us; speedup vs baseline: 13.1251x; 1.4249x over previous
//
#include <hip/hip_runtime.h>
#include <hip/hip_bf16.h>
#include <math.h>

constexpr int BATCH = 1024;
typedef unsigned short u16;
typedef unsigned long long u64;
typedef __attribute__((ext_vector_type(8))) short bf16x8;
typedef __attribute__((ext_vector_type(4))) float f32x4;
typedef __attribute__((ext_vector_type(16))) float f32x16;

__device__ __forceinline__ u16 f2bf(float f) {
    union { __hip_bfloat16 b; u16 s; } u; u.b = __float2bfloat16(f); return u.s;
}
__device__ __forceinline__ f32x4 mfma16(bf16x8 a, bf16x8 b, f32x4 c) {
    return __builtin_amdgcn_mfma_f32_16x16x32_bf16(a, b, c, 0, 0, 0);
}
__device__ __forceinline__ f32x16 mfma32(bf16x8 a, bf16x8 b, f32x16 c) {
    return __builtin_amdgcn_mfma_f32_32x32x16_bf16(a, b, c, 0, 0, 0);
}

// ---------------------------------------------------------------------------
// One-time prep: convert x and ALL weights to bf16 tables in the exact
// layouts the conv kernels' LDS staging expects (so staging = linear b128).
//   Xp  [1024][3600][4]  (pos-major, 4ic bf16, ic3=0)
//   W1t [16][128]   k = tap*4+ic   (pad ic3, taps 25..31 = 0)
//   W2t [32][400]   k = tap*16+ic
//   W3t [64][304]   k = cell*32+ic (pad 288..303 = 0)
//   W4t [128][584]  k = cell*64+ic (pad 576..583 = 0)
//   W1b [1024][3200], W2b [512][1024]  fc weights bf16
// ---------------------------------------------------------------------------
__global__ __launch_bounds__(256)
void prep_all(const float* __restrict__ x,  const float* __restrict__ c1w,
              const float* __restrict__ c2w, const float* __restrict__ c3w,
              const float* __restrict__ c4w, const float* __restrict__ f1w,
              const float* __restrict__ f2w,
              u16* __restrict__ Xp,  u16* __restrict__ W1t, u16* __restrict__ W2t,
              u16* __restrict__ W3t, u16* __restrict__ W4t,
              u16* __restrict__ W1b, u16* __restrict__ W2b)
{
    int id = blockIdx.x * 256 + threadIdx.x;
    constexpr int NX   = 1024 * 3600;   // u64 items
    constexpr int NW1B = 819200;        // float4 items
    constexpr int NW2B = 131072;        // float4 items
    if (id < NX) {
        int img = id / 3600, p = id - img * 3600;
        const float* s = x + (size_t)img * 10800 + p;
        u16 pk[4] = { f2bf(s[0]), f2bf(s[3600]), f2bf(s[7200]), 0 };
        *(u64*)(Xp + (size_t)id * 4) = *(u64*)pk;
        return;
    }
    id -= NX;
    if (id < NW1B) {
        float4 v = ((const float4*)f1w)[id];
        u16 p[4] = { f2bf(v.x), f2bf(v.y), f2bf(v.z), f2bf(v.w) };
        *(u64*)(W1b + (size_t)id * 4) = *(u64*)p;
        return;
    }
    id -= NW1B;
    if (id < NW2B) {
        float4 v = ((const float4*)f2w)[id];
        u16 p[4] = { f2bf(v.x), f2bf(v.y), f2bf(v.z), f2bf(v.w) };
        *(u64*)(W2b + (size_t)id * 4) = *(u64*)p;
        return;
    }
    id -= NW2B;
    if (id < 2048) {                    // W1t
        int oc = id >> 7, k = id & 127, tap = k >> 2, ic = k & 3;
        W1t[id] = (ic < 3 && tap < 25) ? f2bf(c1w[oc * 75 + ic * 25 + tap]) : (u16)0;
        return;
    }
    id -= 2048;
    if (id < 12800) {                   // W2t
        int oc = id / 400, k = id - oc * 400;
        W2t[id] = f2bf(c2w[oc * 400 + (k & 15) * 25 + (k >> 4)]);
        return;
    }
    id -= 12800;
    if (id < 19456) {                   // W3t
        int oc = id / 304, k = id - oc * 304;
        W3t[id] = (k < 288) ? f2bf(c3w[oc * 288 + (k & 31) * 9 + (k >> 5)]) : (u16)0;
        return;
    }
    id -= 19456;
    if (id < 74752) {                   // W4t
        int oc = id / 584, k = id - oc * 584;
        W4t[id] = (k < 576) ? f2bf(c4w[oc * 576 + (k & 63) * 9 + (k >> 6)]) : (u16)0;
    }
}

// ---------------------------------------------------------------------------
// Fused conv1(3->16, 16x16x32 MFMA) + bn1 + conv2(16->32, 32x32x16 MFMA) +
// bn2 + pool.  Block = (img, quadrant), 512 threads = 8 waves.
// All staging now pure linear b128 copies from pre-converted tables.
// LDS: s_c1 28800 | union{s_x 9248 + s_w1 4096 , s_w2t 25600} | bn 576
//    = 54,976 B -> 2 blocks/CU.
// ---------------------------------------------------------------------------
__global__ __launch_bounds__(512, 4)
void conv12_fused(const u16* __restrict__ Xp,
                  const u16* __restrict__ W1t, const u16* __restrict__ W2t,
                  const float* __restrict__ c1b,
                  const float* __restrict__ b1s, const float* __restrict__ b1b,
                  const float* __restrict__ b1m, const float* __restrict__ b1v,
                  const float* __restrict__ c2b,
                  const float* __restrict__ b2s, const float* __restrict__ b2b,
                  const float* __restrict__ b2m, const float* __restrict__ b2v,
                  u16* __restrict__ out)
{
    __shared__ __align__(16) unsigned char S[54976];
    constexpr int U = 28800;                  // union region base
    float* s_bn1 = (float*)(S + 54400);       // [48]
    float* s_bn2 = (float*)(S + 54592);       // [96]

    const int tid = threadIdx.x;
    int bid = blockIdx.x;
    const int qx = bid & 1, qy = (bid >> 1) & 1, img = bid >> 2;

    // ---- phase 0: stage x-tile (b128 from Xp), conv1 weights, bn ----
    const u64* XpI = (const u64*)Xp + (size_t)img * 3600 + (qy * 26) * 60 + qx * 26;
    for (int i = tid; i < 578; i += 512) {          // 34 rows x 17 b128
        int row = i / 17, c2 = i - row * 17;
        *(bf16x8*)(S + U + (row * 34 + c2 * 2) * 8) =
            *(const bf16x8*)(XpI + row * 60 + c2 * 2);
    }
    for (int i = tid; i < 256; i += 512)            // s_w1 [16][128] linear
        *(bf16x8*)(S + U + 9248 + i * 16) = *(const bf16x8*)(W1t + i * 8);
    if (tid < 16) {
        float sc = b1s[tid] * rsqrtf(b1v[tid] + 1e-5f);
        s_bn1[tid] = c1b[tid]; s_bn1[16 + tid] = sc; s_bn1[32 + tid] = b1b[tid] - b1m[tid] * sc;
    } else if (tid >= 32 && tid < 64) {
        int t = tid - 32;
        float sc = b2s[t] * rsqrtf(b2v[t] + 1e-5f);
        s_bn2[t] = c2b[t]; s_bn2[32 + t] = sc; s_bn2[64 + t] = b2b[t] - b2m[t] * sc;
    }
    __syncthreads();

    const int wv = tid >> 6, lr = tid & 15, lg = (tid >> 4) & 3;
    const int o32 = tid & 31, hi = (tid >> 5) & 1;

    // ---- conv1 via MFMA (A = weights -> C[oc][pos]) -> s_c1 pitch-32 ----
    {
        int toff[4][2];
        #pragma unroll
        for (int ks = 0; ks < 4; ++ks)
            #pragma unroll
            for (int h = 0; h < 2; ++h) {
                int t = ks * 8 + lg * 2 + h; if (t > 24) t = 24;
                int ky = t / 5;
                toff[ks][h] = (ky * 34 + (t - ky * 5)) * 8;
            }
        bf16x8 wb[4];
        #pragma unroll
        for (int ks = 0; ks < 4; ++ks)
            wb[ks] = *(const bf16x8*)(S + U + 9248 + lr * 256 + ks * 64 + lg * 16);
        float4 bnB = *(const float4*)(s_bn1 + lg * 4);
        float4 bnS = *(const float4*)(s_bn1 + 16 + lg * 4);
        float4 bnH = *(const float4*)(s_bn1 + 32 + lg * 4);
        #pragma unroll
        for (int mi = 0; mi < 8; ++mi) {
            int t = wv + mi * 8;
            if (t < 57) {
                int pos = t * 16 + lr;
                int pc = pos > 899 ? 899 : pos;
                int py = pc / 30;
                int pb = (py * 34 + (pc - py * 30)) * 8;
                f32x4 a = {0.f, 0.f, 0.f, 0.f};
                #pragma unroll
                for (int ks = 0; ks < 4; ++ks) {
                    union { u64 v[2]; bf16x8 f; } xf;
                    xf.v[0] = *(const u64*)(S + U + pb + toff[ks][0]);
                    xf.v[1] = *(const u64*)(S + U + pb + toff[ks][1]);
                    a = mfma16(wb[ks], xf.f, a);   // A=weights, B=x
                }
                if (pos < 900) {
                    u16 q[4];
                    q[0] = f2bf(fmaxf(a[0] + bnB.x, 0.f) * bnS.x + bnH.x);
                    q[1] = f2bf(fmaxf(a[1] + bnB.y, 0.f) * bnS.y + bnH.y);
                    q[2] = f2bf(fmaxf(a[2] + bnB.z, 0.f) * bnS.z + bnH.z);
                    q[3] = f2bf(fmaxf(a[3] + bnB.w, 0.f) * bnS.w + bnH.w);
                    *(u64*)(S + pos * 32 + lg * 8) = *(u64*)q;
                }
            }
        }
    }
    __syncthreads();

    // ---- stage conv2 weights: s_w2t [32 oc][400 k] linear b128 ----
    for (int i = tid; i < 1600; i += 512)
        *(bf16x8*)(S + U + i * 16) = *(const bf16x8*)(W2t + i * 8);
    __syncthreads();

    // ---- conv2 via 32x32x16 MFMA: 22 M-tiles, NT=3/wave ----
    f32x16 acc[3];
    #pragma unroll
    for (int mi = 0; mi < 3; ++mi)
        #pragma unroll
        for (int j = 0; j < 16; ++j) acc[mi][j] = 0.f;
    int pbase[3];
    #pragma unroll
    for (int mi = 0; mi < 3; ++mi) {
        int tt = wv + mi * 8; if (tt > 21) tt = 21;
        int row = tt * 32 + o32;
        int q = row >> 2; if (q > 168) q = 168;
        int Q = row & 3;
        int y2 = 2 * (q / 13) + (Q >> 1);
        int x2 = 2 * (q - (q / 13) * 13) + (Q & 1);
        pbase[mi] = (y2 * 30 + x2) * 32 + hi * 16;
    }
    const unsigned char* wrow = S + U + o32 * 800 + hi * 16;
    #pragma unroll
    for (int ks = 0; ks < 25; ++ks) {
        bf16x8 b = *(const bf16x8*)(wrow + ks * 32);
        const int dp = ((ks / 5) * 30 + (ks % 5)) * 32;
        #pragma unroll
        for (int mi = 0; mi < 3; ++mi) {
            bf16x8 a = *(const bf16x8*)(S + pbase[mi] + dp);
            acc[mi] = mfma32(a, b, acc[mi]);
        }
    }
    // ---- epilogue: bias -> relu -> bn -> in-lane 2x2 pool ----
    u16* outI = out + (size_t)img * 676 * 32;
    float bnb = s_bn2[o32], bns = s_bn2[32 + o32], bnh = s_bn2[64 + o32];
    #pragma unroll
    for (int mi = 0; mi < 3; ++mi) {
        int tt = wv + mi * 8;
        if (tt < 22) {
            #pragma unroll
            for (int rg = 0; rg < 4; ++rg) {
                int quad = tt * 8 + 2 * rg + hi;
                if (quad < 169) {
                    float m = -3.4e38f;
                    #pragma unroll
                    for (int r = 0; r < 4; ++r)
                        m = fmaxf(m, fmaxf(acc[mi][rg * 4 + r] + bnb, 0.f) * bns + bnh);
                    int py = quad / 13, px = quad - (quad / 13) * 13;
                    int gpos = (qy * 13 + py) * 26 + qx * 13 + px;
                    outI[gpos * 32 + o32] = f2bf(m);
                }
            }
        }
    }
}

// ---------------------------------------------------------------------------
// conv3 via 32x32x16: 32->64, 3x3, 26->24, pool->12. Block=(img, oc-half),
// 576 threads = 9 waves, 18 M-tiles -> exactly 2 per wave.
// Weights staged as linear b128 from W3t (pre-padded pitch 304).
// ---------------------------------------------------------------------------
__global__ __launch_bounds__(576, 2)
void conv3_mfma(const u16* __restrict__ in, const u16* __restrict__ W3t,
                const float* __restrict__ cbias,
                const float* __restrict__ bns, const float* __restrict__ bnb,
                const float* __restrict__ bnm, const float* __restrict__ bnv,
                u16* __restrict__ out)
{
    __shared__ __align__(16) unsigned char S[63104];
    float* s_bn = (float*)(S + 62720);

    const int tid = threadIdx.x;
    const int ocg = blockIdx.x & 1;
    const int img = blockIdx.x >> 1;

    const u16* inI = in + (size_t)img * 676 * 32;
    for (int g = tid; g < 2704; g += 576) {
        int pa = g * 16;
        int off = pa ^ ((pa >> 2) & 0x20);
        *(bf16x8*)(S + off) = *(const bf16x8*)(inI + g * 8);
    }
    const u16* wsrc = W3t + ocg * 32 * 304;
    for (int i = tid; i < 1216; i += 576)
        *(bf16x8*)(S + 43264 + i * 16) = *(const bf16x8*)(wsrc + i * 8);
    if (tid < 32) {
        int oc = ocg * 32 + tid;
        float sc = bns[oc] * rsqrtf(bnv[oc] + 1e-5f);
        s_bn[tid] = cbias[oc]; s_bn[32 + tid] = sc; s_bn[64 + tid] = bnb[oc] - bnm[oc] * sc;
    }
    __syncthreads();

    const int wv = tid >> 6;
    const int o32 = tid & 31, hi = (tid >> 5) & 1;
    f32x16 acc[2];
    #pragma unroll
    for (int mi = 0; mi < 2; ++mi)
        #pragma unroll
        for (int j = 0; j < 16; ++j) acc[mi][j] = 0.f;
    int pbase[2];
    #pragma unroll
    for (int mi = 0; mi < 2; ++mi) {
        int tt = wv * 2 + mi;
        int row = tt * 32 + o32;
        int q = row >> 2, Q = row & 3;
        int y2 = 2 * (q / 12) + (Q >> 1);
        int x2 = 2 * (q - (q / 12) * 12) + (Q & 1);
        pbase[mi] = (y2 * 26 + x2) * 64 + hi * 16;
    }
    const unsigned char* wrow = S + 43264 + o32 * 608 + hi * 16;
    #pragma unroll
    for (int s = 0; s < 18; ++s) {
        bf16x8 b = *(const bf16x8*)(wrow + s * 32);
        const int cell = s >> 1;
        const int dp = ((cell / 3) * 26 + (cell % 3)) * 64 + (s & 1) * 32;
        #pragma unroll
        for (int mi = 0; mi < 2; ++mi) {
            int pa = pbase[mi] + dp;
            bf16x8 a = *(const bf16x8*)(S + (pa ^ ((pa >> 2) & 0x20)));
            acc[mi] = mfma32(a, b, acc[mi]);
        }
    }
    u16* outI = out + (size_t)img * 144 * 64 + ocg * 32;
    float bnbv = s_bn[o32], bnsv = s_bn[32 + o32], bnhv = s_bn[64 + o32];
    #pragma unroll
    for (int mi = 0; mi < 2; ++mi) {
        int tt = wv * 2 + mi;
        #pragma unroll
        for (int rg = 0; rg < 4; ++rg) {
            int quad = tt * 8 + 2 * rg + hi;
            float m = -3.4e38f;
            #pragma unroll
            for (int r = 0; r < 4; ++r)
                m = fmaxf(m, fmaxf(acc[mi][rg * 4 + r] + bnbv, 0.f) * bnsv + bnhv);
            outI[quad * 64 + o32] = f2bf(m);
        }
    }
}

// ---------------------------------------------------------------------------
// conv4 MFMA: 64->128, 3x3, 12->10, pool->5. Weights staged linear from W4t.
// ---------------------------------------------------------------------------
__global__ __launch_bounds__(256)
void conv4_mfma(const u16* __restrict__ in, const u16* __restrict__ W4t,
                const float* __restrict__ cbias,
                const float* __restrict__ bns, const float* __restrict__ bnb,
                const float* __restrict__ bnm, const float* __restrict__ bnv,
                u16* __restrict__ out)
{
    __shared__ __align__(16) unsigned char S[56192];
    float* s_bn = (float*)(S + 55808);

    const int tid = threadIdx.x;
    const int ocg = blockIdx.x & 3;
    const int img = blockIdx.x >> 2;

    const u16* inI = in + (size_t)img * 144 * 64;
    for (int g = tid; g < 144 * 8; g += 256) {
        int pos = g >> 3, part = g & 7;
        int off = (pos * 128 + part * 16) ^ ((pos & 7) << 4);
        *(bf16x8*)(S + off) = *(const bf16x8*)(inI + g * 8);
    }
    const u16* wsrc = W4t + ocg * 32 * 584;
    for (int i = tid; i < 2336; i += 256)
        *(bf16x8*)(S + 18432 + i * 16) = *(const bf16x8*)(wsrc + i * 8);
    if (tid < 32) {
        int oc = ocg * 32 + tid;
        float sc = bns[oc] * rsqrtf(bnv[oc] + 1e-5f);
        s_bn[tid] = cbias[oc]; s_bn[32 + tid] = sc; s_bn[64 + tid] = bnb[oc] - bnm[oc] * sc;
    }
    __syncthreads();

    const int w = tid >> 6, lr = tid & 15, lg = (tid >> 4) & 3;
    f32x4 acc[2][2];
    {
        f32x4 z = {0.f, 0.f, 0.f, 0.f};
        acc[0][0] = z; acc[0][1] = z; acc[1][0] = z; acc[1][1] = z;
    }
    int pb7[2];
    #pragma unroll
    for (int mi = 0; mi < 2; ++mi) {
        int aq = (w + mi * 4) * 4 + (lr >> 2);
        if (aq > 24) aq = 24;
        int y2 = 2 * (aq / 5) + ((lr >> 1) & 1);
        int x2 = 2 * (aq % 5) + (lr & 1);
        pb7[mi] = ((y2 * 12 + x2) << 7) + lg * 16;
    }
    #pragma unroll
    for (int ks = 0; ks < 18; ++ks) {
        bf16x8 b0 = *(const bf16x8*)(S + 18432 + lr * 1168 + ks * 64 + lg * 16);
        bf16x8 b1 = *(const bf16x8*)(S + 18432 + (16 + lr) * 1168 + ks * 64 + lg * 16);
        const int cell = ks >> 1;
        const int dp7 = (((cell / 3) * 12 + (cell % 3)) << 7) + (ks & 1) * 64;
        #pragma unroll
        for (int mi = 0; mi < 2; ++mi) {
            int pa = pb7[mi] + dp7;
            int off = pa ^ ((pa >> 3) & 0x70);
            bf16x8 a = *(const bf16x8*)(S + off);
            acc[mi][0] = mfma16(a, b0, acc[mi][0]);
            acc[mi][1] = mfma16(a, b1, acc[mi][1]);
        }
    }
    u16* outI = out + (size_t)img * 3200;
    float bc0 = s_bn[lr],      sc0 = s_bn[32 + lr], sh0 = s_bn[64 + lr];
    float bc1 = s_bn[16 + lr], sc1 = s_bn[48 + lr], sh1 = s_bn[80 + lr];
    #pragma unroll
    for (int mi = 0; mi < 2; ++mi) {
        int quad = (w + mi * 4) * 4 + lg;
        if (quad < 25) {
            float m0 = -3.4e38f, m1 = -3.4e38f;
            #pragma unroll
            for (int r2 = 0; r2 < 4; ++r2) {
                m0 = fmaxf(m0, fmaxf(acc[mi][0][r2] + bc0, 0.f) * sc0 + sh0);
                m1 = fmaxf(m1, fmaxf(acc[mi][1][r2] + bc1, 0.f) * sc1 + sh1);
            }
            outI[(ocg * 32 + lr) * 25 + quad]      = f2bf(m0);
            outI[(ocg * 32 + 16 + lr) * 25 + quad] = f2bf(m1);
        }
    }
}

// ---------------------------------------------------------------------------
// fc GEMM, both operands bf16 (unchanged).
// ---------------------------------------------------------------------------
template<bool OUTF32>
__global__ __launch_bounds__(256)
void fc_gemm_bf(const u16* __restrict__ A, const u16* __restrict__ Wb,
                const float* __restrict__ bias, void* __restrict__ outv,
                int M, int N, int K)
{
    __shared__ __align__(16) unsigned char S[34816];   // sA 64x272 | sB 64x272
    const int tid = threadIdx.x;
    const int n0 = blockIdx.x * 64, m0 = blockIdx.y * 64;
    const int w = tid >> 6, lr = tid & 15, lg = (tid >> 4) & 3;
    const int r = tid >> 2, c = tid & 3;

    f32x4 acc[4];
    { f32x4 z = {0.f,0.f,0.f,0.f}; acc[0]=z; acc[1]=z; acc[2]=z; acc[3]=z; }

    const u16* Ab = A  + (size_t)(m0 + r) * K + c * 8;
    const u16* Bb = Wb + (size_t)(n0 + r) * K + c * 8;
    unsigned char* sAw = S + r * 272 + c * 16;
    unsigned char* sBw = S + 17408 + r * 272 + c * 16;

    for (int k0 = 0; k0 < K; k0 += 128) {
        #pragma unroll
        for (int q = 0; q < 4; ++q) {
            *(bf16x8*)(sAw + q * 64) = *(const bf16x8*)(Ab + k0 + q * 32);
            *(bf16x8*)(sBw + q * 64) = *(const bf16x8*)(Bb + k0 + q * 32);
        }
        __syncthreads();
        #pragma unroll
        for (int k32 = 0; k32 < 4; ++k32) {
            bf16x8 a = *(const bf16x8*)(S + (w * 16 + lr) * 272 + k32 * 64 + lg * 16);
            #pragma unroll
            for (int nt = 0; nt < 4; ++nt) {
                bf16x8 b = *(const bf16x8*)(S + 17408 + (nt * 16 + lr) * 272 + k32 * 64 + lg * 16);
                acc[nt] = mfma16(a, b, acc[nt]);
            }
        }
        __syncthreads();
    }
    #pragma unroll
    for (int nt = 0; nt < 4; ++nt) {
        int col = n0 + nt * 16 + lr;
        float bv = bias[col];
        #pragma unroll
        for (int r2 = 0; r2 < 4; ++r2) {
            int row = m0 + w * 16 + lg * 4 + r2;
            float v = fmaxf(acc[nt][r2] + bv, 0.f);
            if (OUTF32) ((float*)outv)[(size_t)row * N + col] = v;
            else        ((u16*)outv)[(size_t)row * N + col] = f2bf(v);
        }
    }
}

// ---------------------------------------------------------------------------
// Fused fc3 (512->37) + sigmoid + sequential normalize + dep-multiply.
// ---------------------------------------------------------------------------
__global__ __launch_bounds__(256)
void fc3_norm(const float* __restrict__ A, const float* __restrict__ W,
              const float* __restrict__ bias, float* __restrict__ out)
{
    __shared__ float sp[4][40];
    const int v = threadIdx.x >> 6, lane = threadIdx.x & 63;
    const int img = blockIdx.x * 4 + v;

    if (lane < 37) {
        const float4* a4 = (const float4*)(A + (size_t)img * 512);
        const float4* w4 = (const float4*)(W + (size_t)lane * 512);
        float s = bias[lane];
        #pragma unroll 4
        for (int k = 0; k < 128; ++k) {
            float4 a = a4[k], ww = w4[k];
            s = fmaf(a.x, ww.x, s); s = fmaf(a.y, ww.y, s);
            s = fmaf(a.z, ww.z, s); s = fmaf(a.w, ww.w, s);
        }
        sp[v][lane] = 1.f / (1.f + expf(-s));
    }
    __syncthreads();
    if (lane == 0) {
        float xv[37];
        #pragma unroll
        for (int i = 0; i < 37; ++i) xv[i] = sp[v][i];
        const int ss[11]  = {0, 3, 5, 7, 9, 13, 15, 18, 25, 28, 31};
        const int ee[11]  = {3, 5, 7, 9, 13, 15, 18, 25, 28, 31, 37};
        const int dep[11] = {-1, 1, 4, 4, 4, -1, 0, 13, 3, 7, 7};
        #pragma unroll
        for (int i = 0; i < 11; ++i) {
            for (int j = ss[i]; j < ee[i]; ++j) {
                float ssum = 0.f;
                for (int cix = ss[i]; cix < ee[i]; ++cix) ssum += xv[cix];
                xv[j] = xv[j] / (ssum + 1e-12f);
            }
        }
        #pragma unroll
        for (int i = 0; i < 11; ++i) {
            if (dep[i] >= 0) {
                const float m = xv[dep[i]];
                for (int cix = ss[i]; cix < ee[i]; ++cix) xv[cix] *= m;
            }
        }
        #pragma unroll
        for (int i = 0; i < 37; ++i) sp[v][i] = xv[i];
    }
    __syncthreads();
    if (lane < 37) out[(size_t)img * 37 + lane] = sp[v][lane];
}

// ---------------------------------------------------------------------------
extern "C" void kernel_launch(void* const* d_in, const int* in_sizes, int n_in,
                              void* d_out, int out_size, void* d_ws, size_t ws_size,
                              hipStream_t stream)
{
    const float* x   = (const float*)d_in[0];
    const float* c1w = (const float*)d_in[1];  const float* c1b = (const float*)d_in[2];
    const float* b1s = (const float*)d_in[3];  const float* b1b = (const float*)d_in[4];
    const float* b1m = (const float*)d_in[5];  const float* b1v = (const float*)d_in[6];
    const float* c2w = (const float*)d_in[7];  const float* c2b = (const float*)d_in[8];
    const float* b2s = (const float*)d_in[9];  const float* b2b = (const float*)d_in[10];
    const float* b2m = (const float*)d_in[11]; const float* b2v = (const float*)d_in[12];
    const float* c3w = (const float*)d_in[13]; const float* c3b = (const float*)d_in[14];
    const float* b3s = (const float*)d_in[15]; const float* b3b = (const float*)d_in[16];
    const float* b3m = (const float*)d_in[17]; const float* b3v = (const float*)d_in[18];
    const float* c4w = (const float*)d_in[19]; const float* c4b = (const float*)d_in[20];
    const float* b4s = (const float*)d_in[21]; const float* b4b = (const float*)d_in[22];
    const float* b4m = (const float*)d_in[23]; const float* b4v = (const float*)d_in[24];
    const float* f1w = (const float*)d_in[25]; const float* f1b = (const float*)d_in[26];
    const float* f2w = (const float*)d_in[27]; const float* f2b = (const float*)d_in[28];
    const float* f3w = (const float*)d_in[29]; const float* f3b = (const float*)d_in[30];

    // Workspace (bytes), peak 81.75 MB (< 82.6 MB proven in Round 2):
    //   P2  bf16 [1024][676][32]  @ 0           44,302,336
    //   Xp  bf16 [1024][3600][4]  @ 44,302,336  29,491,200  (dead after conv12)
    //   P3  bf16 [1024][144][64]  @ 44,302,336  18,874,368  (overlays Xp)
    //   P4  bf16 [1024][3200]     @ 63,176,704   6,553,600  (overlays Xp)
    //   F1  bf16 [1024][1024]     @ 69,730,304   2,097,152  (overlays Xp)
    //   F2  f32  [1024][512]      @ 71,827,456   2,097,152  (overlays Xp tail)
    //   W1b bf16 [1024][3200]     @ 73,924,608   6,553,600
    //   W2b bf16 [512][1024]      @ 80,478,208   1,048,576
    //   W1t bf16 [16][128]        @ 81,526,784       4,096
    //   W2t bf16 [32][400]        @ 81,530,880      25,600
    //   W3t bf16 [64][304]        @ 81,556,480      38,912
    //   W4t bf16 [128][584]       @ 81,595,392     149,504
    u16*   P2  = (u16*)d_ws;
    u16*   Xp  = (u16*)((char*)d_ws + 44302336);
    u16*   P3  = (u16*)((char*)d_ws + 44302336);
    u16*   P4  = (u16*)((char*)d_ws + 63176704);
    u16*   F1  = (u16*)((char*)d_ws + 69730304);
    float* F2  = (float*)((char*)d_ws + 71827456);
    u16*   W1b = (u16*)((char*)d_ws + 73924608);
    u16*   W2b = (u16*)((char*)d_ws + 80478208);
    u16*   W1t = (u16*)((char*)d_ws + 81526784);
    u16*   W2t = (u16*)((char*)d_ws + 81530880);
    u16*   W3t = (u16*)((char*)d_ws + 81556480);
    u16*   W4t = (u16*)((char*)d_ws + 81595392);

    // total prep items = 3,686,400 + 819,200 + 131,072 + 109,056 = 4,745,728
    prep_all<<<4745728 / 256, 256, 0, stream>>>(x, c1w, c2w, c3w, c4w, f1w, f2w,
                                                Xp, W1t, W2t, W3t, W4t, W1b, W2b);

    conv12_fused<<<BATCH * 4, 512, 0, stream>>>(Xp, W1t, W2t, c1b, b1s, b1b, b1m, b1v,
                                                c2b, b2s, b2b, b2m, b2v, P2);
    conv3_mfma<<<BATCH * 2, 576, 0, stream>>>(P2, W3t, c3b, b3s, b3b, b3m, b3v, P3);
    conv4_mfma<<<BATCH * 4, 256, 0, stream>>>(P3, W4t, c4b, b4s, b4b, b4m, b4v, P4);

    fc_gemm_bf<false><<<dim3(16, 16), 256, 0, stream>>>(P4, W1b, f1b, F1, 1024, 1024, 3200);
    fc_gemm_bf<true ><<<dim3(8, 16),  256, 0, stream>>>(F1, W2b, f2b, F2, 1024, 512, 1024);
    fc3_norm<<<BATCH / 4, 256, 0, stream>>>(F2, f3w, f3b, (float*)d_out);
}

// Round 9
// 245.773 us; speedup vs baseline: 14.3408x; 1.0926x over previous
//
#include <hip/hip_runtime.h>
#include <hip/hip_bf16.h>
#include <math.h>

constexpr int BATCH = 1024;
typedef unsigned short u16;
typedef unsigned long long u64;
typedef __attribute__((ext_vector_type(8))) short bf16x8;
typedef __attribute__((ext_vector_type(4))) float f32x4;
typedef __attribute__((ext_vector_type(16))) float f32x16;

__device__ __forceinline__ u16 f2bf(float f) {
    union { __hip_bfloat16 b; u16 s; } u; u.b = __float2bfloat16(f); return u.s;
}
__device__ __forceinline__ f32x4 mfma16(bf16x8 a, bf16x8 b, f32x4 c) {
    return __builtin_amdgcn_mfma_f32_16x16x32_bf16(a, b, c, 0, 0, 0);
}
__device__ __forceinline__ f32x16 mfma32(bf16x8 a, bf16x8 b, f32x16 c) {
    return __builtin_amdgcn_mfma_f32_32x32x16_bf16(a, b, c, 0, 0, 0);
}

// ---------------------------------------------------------------------------
// One-time prep. Weight tables are K-MAJOR so a wave's per-k-slice B-load is
// one fully-coalesced 1024B global read (weights stay in L2, NOT LDS):
//   Xp  [1024][3600][4]  x, pos-major 4ic bf16 (ic3=0)
//   W1t [16][128]        conv1, k = tap*4+ic (LDS-staged, tiny)
//   W2g [25][32 oc][16]  conv2, slice ks: val[o32][k=ks*16+hi*8+j]
//   W3g [2][18][32][16]  conv3, per ocg, slice s: k = s*16+hi*8+j
//   W4g [4][18][2][16][4][8] conv4, per ocg/ks/half: [lr][lg][j], k=ks*32+lg*8+j
//   W1b [1024][3200], W2b [512][1024]  fc weights bf16
// ---------------------------------------------------------------------------
__global__ __launch_bounds__(256)
void prep_all(const float* __restrict__ x,  const float* __restrict__ c1w,
              const float* __restrict__ c2w, const float* __restrict__ c3w,
              const float* __restrict__ c4w, const float* __restrict__ f1w,
              const float* __restrict__ f2w,
              u16* __restrict__ Xp,  u16* __restrict__ W1t, u16* __restrict__ W2g,
              u16* __restrict__ W3g, u16* __restrict__ W4g,
              u16* __restrict__ W1b, u16* __restrict__ W2b)
{
    int id = blockIdx.x * 256 + threadIdx.x;
    constexpr int NX   = 1024 * 3600;   // u64 items
    constexpr int NW1B = 819200;        // float4 items
    constexpr int NW2B = 131072;        // float4 items
    if (id < NX) {
        int img = id / 3600, p = id - img * 3600;
        const float* s = x + (size_t)img * 10800 + p;
        u16 pk[4] = { f2bf(s[0]), f2bf(s[3600]), f2bf(s[7200]), 0 };
        *(u64*)(Xp + (size_t)id * 4) = *(u64*)pk;
        return;
    }
    id -= NX;
    if (id < NW1B) {
        float4 v = ((const float4*)f1w)[id];
        u16 p[4] = { f2bf(v.x), f2bf(v.y), f2bf(v.z), f2bf(v.w) };
        *(u64*)(W1b + (size_t)id * 4) = *(u64*)p;
        return;
    }
    id -= NW1B;
    if (id < NW2B) {
        float4 v = ((const float4*)f2w)[id];
        u16 p[4] = { f2bf(v.x), f2bf(v.y), f2bf(v.z), f2bf(v.w) };
        *(u64*)(W2b + (size_t)id * 4) = *(u64*)p;
        return;
    }
    id -= NW2B;
    if (id < 2048) {                    // W1t [16][128]
        int oc = id >> 7, k = id & 127, tap = k >> 2, ic = k & 3;
        W1t[id] = (ic < 3 && tap < 25) ? f2bf(c1w[oc * 75 + ic * 25 + tap]) : (u16)0;
        return;
    }
    id -= 2048;
    if (id < 12800) {                   // W2g: ks*512 + o32*16 + hi*8 + j
        int ks = id / 512, r = id & 511;
        int o32 = r >> 4, hi = (r >> 3) & 1, j = r & 7;
        int k = ks * 16 + hi * 8 + j;
        W2g[id] = f2bf(c2w[o32 * 400 + (k & 15) * 25 + (k >> 4)]);
        return;
    }
    id -= 12800;
    if (id < 18432) {                   // W3g: ocg*9216 + s*512 + o32*16 + hi*8 + j
        int ocg = id / 9216, r = id % 9216;
        int s = r / 512, r2 = r & 511;
        int o32 = r2 >> 4, hi = (r2 >> 3) & 1, j = r2 & 7;
        int k = s * 16 + hi * 8 + j;    // < 288 always
        W3g[id] = f2bf(c3w[(ocg * 32 + o32) * 288 + (k & 31) * 9 + (k >> 5)]);
        return;
    }
    id -= 18432;
    if (id < 73728) {                   // W4g: ((ocg*18+ks)*2+half)*512 + (lr*4+lg)*8 + j
        int ocg = id / 18432, r = id % 18432;
        int ks = r / 1024, r2 = r & 1023;
        int half = r2 >> 9, r3 = r2 & 511;
        int lr = r3 >> 5, r4 = r3 & 31;
        int lg = r4 >> 3, j = r4 & 7;
        int k = ks * 32 + lg * 8 + j;   // < 576 always
        int oc = ocg * 32 + half * 16 + lr;
        W4g[id] = f2bf(c4w[oc * 576 + (k & 63) * 9 + (k >> 6)]);
    }
}

// ---------------------------------------------------------------------------
// Fused conv1(3->16, 16x16x32 MFMA) + bn1 + conv2(16->32, 32x32x16 MFMA) +
// bn2 + pool.  Block = (img, quadrant), 512 threads = 8 waves.
// conv2 weights read per-tap from L2 (coalesced 1KB wave-loads) -> LDS pipe
// reserved for A-reads; LDS 42,720 B -> 3 blocks/CU.
// ---------------------------------------------------------------------------
__global__ __launch_bounds__(512, 6)
void conv12_fused(const u16* __restrict__ Xp,
                  const u16* __restrict__ W1t, const u16* __restrict__ W2g,
                  const float* __restrict__ c1b,
                  const float* __restrict__ b1s, const float* __restrict__ b1b,
                  const float* __restrict__ b1m, const float* __restrict__ b1v,
                  const float* __restrict__ c2b,
                  const float* __restrict__ b2s, const float* __restrict__ b2b,
                  const float* __restrict__ b2m, const float* __restrict__ b2v,
                  u16* __restrict__ out)
{
    __shared__ __align__(16) unsigned char S[42720];
    // 0      : s_c1 [900 pos][16 ch] pitch 32B     28800
    // 28800  : s_x  [34*34][4 ic] u64               9248
    // 38048  : s_w1 [16][128]                       4096
    // 42144  : bn1 [48] ; 42336 : bn2 [96]
    float* s_bn1 = (float*)(S + 42144);
    float* s_bn2 = (float*)(S + 42336);

    const int tid = threadIdx.x;
    int bid = blockIdx.x;
    const int qx = bid & 1, qy = (bid >> 1) & 1, img = bid >> 2;

    // ---- phase 0: stage x-tile + conv1 weights (linear b128), bn ----
    const u64* XpI = (const u64*)Xp + (size_t)img * 3600 + (qy * 26) * 60 + qx * 26;
    for (int i = tid; i < 578; i += 512) {          // 34 rows x 17 b128
        int row = i / 17, c2 = i - row * 17;
        *(bf16x8*)(S + 28800 + (row * 34 + c2 * 2) * 8) =
            *(const bf16x8*)(XpI + row * 60 + c2 * 2);
    }
    for (int i = tid; i < 256; i += 512)
        *(bf16x8*)(S + 38048 + i * 16) = *(const bf16x8*)(W1t + i * 8);
    if (tid < 16) {
        float sc = b1s[tid] * rsqrtf(b1v[tid] + 1e-5f);
        s_bn1[tid] = c1b[tid]; s_bn1[16 + tid] = sc; s_bn1[32 + tid] = b1b[tid] - b1m[tid] * sc;
    } else if (tid >= 32 && tid < 64) {
        int t = tid - 32;
        float sc = b2s[t] * rsqrtf(b2v[t] + 1e-5f);
        s_bn2[t] = c2b[t]; s_bn2[32 + t] = sc; s_bn2[64 + t] = b2b[t] - b2m[t] * sc;
    }
    __syncthreads();

    const int wv = tid >> 6, lr = tid & 15, lg = (tid >> 4) & 3;
    const int o32 = tid & 31, hi = (tid >> 5) & 1;

    // ---- conv1 via MFMA (A = weights -> C[oc][pos]) -> s_c1 pitch-32 ----
    {
        int toff[4][2];
        #pragma unroll
        for (int ks = 0; ks < 4; ++ks)
            #pragma unroll
            for (int h = 0; h < 2; ++h) {
                int t = ks * 8 + lg * 2 + h; if (t > 24) t = 24;
                int ky = t / 5;
                toff[ks][h] = (ky * 34 + (t - ky * 5)) * 8;
            }
        bf16x8 wb[4];
        #pragma unroll
        for (int ks = 0; ks < 4; ++ks)
            wb[ks] = *(const bf16x8*)(S + 38048 + lr * 256 + ks * 64 + lg * 16);
        float4 bnB = *(const float4*)(s_bn1 + lg * 4);
        float4 bnS = *(const float4*)(s_bn1 + 16 + lg * 4);
        float4 bnH = *(const float4*)(s_bn1 + 32 + lg * 4);
        #pragma unroll
        for (int mi = 0; mi < 8; ++mi) {
            int t = wv + mi * 8;
            if (t < 57) {
                int pos = t * 16 + lr;
                int pc = pos > 899 ? 899 : pos;
                int py = pc / 30;
                int pb = (py * 34 + (pc - py * 30)) * 8;
                f32x4 a = {0.f, 0.f, 0.f, 0.f};
                #pragma unroll
                for (int ks = 0; ks < 4; ++ks) {
                    union { u64 v[2]; bf16x8 f; } xf;
                    xf.v[0] = *(const u64*)(S + 28800 + pb + toff[ks][0]);
                    xf.v[1] = *(const u64*)(S + 28800 + pb + toff[ks][1]);
                    a = mfma16(wb[ks], xf.f, a);   // A=weights, B=x
                }
                if (pos < 900) {
                    u16 q[4];
                    q[0] = f2bf(fmaxf(a[0] + bnB.x, 0.f) * bnS.x + bnH.x);
                    q[1] = f2bf(fmaxf(a[1] + bnB.y, 0.f) * bnS.y + bnH.y);
                    q[2] = f2bf(fmaxf(a[2] + bnB.z, 0.f) * bnS.z + bnH.z);
                    q[3] = f2bf(fmaxf(a[3] + bnB.w, 0.f) * bnS.w + bnH.w);
                    *(u64*)(S + pos * 32 + lg * 8) = *(u64*)q;
                }
            }
        }
    }
    __syncthreads();

    // ---- conv2 via 32x32x16 MFMA: 22 M-tiles, NT=3/wave; B from L2 ----
    f32x16 acc[3];
    #pragma unroll
    for (int mi = 0; mi < 3; ++mi)
        #pragma unroll
        for (int j = 0; j < 16; ++j) acc[mi][j] = 0.f;
    int pbase[3];
    #pragma unroll
    for (int mi = 0; mi < 3; ++mi) {
        int tt = wv + mi * 8; if (tt > 21) tt = 21;
        int row = tt * 32 + o32;
        int q = row >> 2; if (q > 168) q = 168;
        int Q = row & 3;
        int y2 = 2 * (q / 13) + (Q >> 1);
        int x2 = 2 * (q - (q / 13) * 13) + (Q & 1);
        pbase[mi] = (y2 * 30 + x2) * 32 + hi * 16;
    }
    const bf16x8* W2v = (const bf16x8*)W2g;
    const int bidx = o32 * 2 + hi;
    #pragma unroll
    for (int ks = 0; ks < 25; ++ks) {
        bf16x8 b = W2v[ks * 64 + bidx];
        const int dp = ((ks / 5) * 30 + (ks % 5)) * 32;
        #pragma unroll
        for (int mi = 0; mi < 3; ++mi) {
            bf16x8 a = *(const bf16x8*)(S + pbase[mi] + dp);
            acc[mi] = mfma32(a, b, acc[mi]);
        }
    }
    // ---- epilogue: bias -> relu -> bn -> in-lane 2x2 pool ----
    u16* outI = out + (size_t)img * 676 * 32;
    float bnb = s_bn2[o32], bns = s_bn2[32 + o32], bnh = s_bn2[64 + o32];
    #pragma unroll
    for (int mi = 0; mi < 3; ++mi) {
        int tt = wv + mi * 8;
        if (tt < 22) {
            #pragma unroll
            for (int rg = 0; rg < 4; ++rg) {
                int quad = tt * 8 + 2 * rg + hi;
                if (quad < 169) {
                    float m = -3.4e38f;
                    #pragma unroll
                    for (int r = 0; r < 4; ++r)
                        m = fmaxf(m, fmaxf(acc[mi][rg * 4 + r] + bnb, 0.f) * bns + bnh);
                    int py = quad / 13, px = quad - (quad / 13) * 13;
                    int gpos = (qy * 13 + py) * 26 + qx * 13 + px;
                    outI[gpos * 32 + o32] = f2bf(m);
                }
            }
        }
    }
}

// ---------------------------------------------------------------------------
// conv3 via 32x32x16: 32->64, 3x3, 26->24, pool->12. Block=(img, oc-half),
// 576 threads = 9 waves, 18 M-tiles = 2/wave. Weights from L2 (coalesced).
// LDS 43,648 B -> 3 blocks/CU (27 waves).
// ---------------------------------------------------------------------------
__global__ __launch_bounds__(576, 6)
void conv3_mfma(const u16* __restrict__ in, const u16* __restrict__ W3g,
                const float* __restrict__ cbias,
                const float* __restrict__ bns, const float* __restrict__ bnb,
                const float* __restrict__ bnm, const float* __restrict__ bnv,
                u16* __restrict__ out)
{
    __shared__ __align__(16) unsigned char S[43648];
    float* s_bn = (float*)(S + 43264);

    const int tid = threadIdx.x;
    const int ocg = blockIdx.x & 1;
    const int img = blockIdx.x >> 1;

    const u16* inI = in + (size_t)img * 676 * 32;
    for (int g = tid; g < 2704; g += 576) {
        int pa = g * 16;
        int off = pa ^ ((pa >> 2) & 0x20);
        *(bf16x8*)(S + off) = *(const bf16x8*)(inI + g * 8);
    }
    if (tid < 32) {
        int oc = ocg * 32 + tid;
        float sc = bns[oc] * rsqrtf(bnv[oc] + 1e-5f);
        s_bn[tid] = cbias[oc]; s_bn[32 + tid] = sc; s_bn[64 + tid] = bnb[oc] - bnm[oc] * sc;
    }
    __syncthreads();

    const int wv = tid >> 6;
    const int o32 = tid & 31, hi = (tid >> 5) & 1;
    f32x16 acc[2];
    #pragma unroll
    for (int mi = 0; mi < 2; ++mi)
        #pragma unroll
        for (int j = 0; j < 16; ++j) acc[mi][j] = 0.f;
    int pbase[2];
    #pragma unroll
    for (int mi = 0; mi < 2; ++mi) {
        int tt = wv * 2 + mi;
        int row = tt * 32 + o32;
        int q = row >> 2, Q = row & 3;
        int y2 = 2 * (q / 12) + (Q >> 1);
        int x2 = 2 * (q - (q / 12) * 12) + (Q & 1);
        pbase[mi] = (y2 * 26 + x2) * 64 + hi * 16;
    }
    const bf16x8* W3v = (const bf16x8*)W3g;
    const int bidx = ocg * 1152 + o32 * 2 + hi;
    #pragma unroll
    for (int s = 0; s < 18; ++s) {
        bf16x8 b = W3v[bidx + s * 64];
        const int cell = s >> 1;
        const int dp = ((cell / 3) * 26 + (cell % 3)) * 64 + (s & 1) * 32;
        #pragma unroll
        for (int mi = 0; mi < 2; ++mi) {
            int pa = pbase[mi] + dp;
            bf16x8 a = *(const bf16x8*)(S + (pa ^ ((pa >> 2) & 0x20)));
            acc[mi] = mfma32(a, b, acc[mi]);
        }
    }
    u16* outI = out + (size_t)img * 144 * 64 + ocg * 32;
    float bnbv = s_bn[o32], bnsv = s_bn[32 + o32], bnhv = s_bn[64 + o32];
    #pragma unroll
    for (int mi = 0; mi < 2; ++mi) {
        int tt = wv * 2 + mi;
        #pragma unroll
        for (int rg = 0; rg < 4; ++rg) {
            int quad = tt * 8 + 2 * rg + hi;
            float m = -3.4e38f;
            #pragma unroll
            for (int r = 0; r < 4; ++r)
                m = fmaxf(m, fmaxf(acc[mi][rg * 4 + r] + bnbv, 0.f) * bnsv + bnhv);
            outI[quad * 64 + o32] = f2bf(m);
        }
    }
}

// ---------------------------------------------------------------------------
// conv4 MFMA16: 64->128, 3x3, 12->10, pool->5. Weights from L2 (coalesced).
// LDS 18,816 B -> 8 blocks/CU = 32 waves (was 8).
// ---------------------------------------------------------------------------
__global__ __launch_bounds__(256, 8)
void conv4_mfma(const u16* __restrict__ in, const u16* __restrict__ W4g,
                const float* __restrict__ cbias,
                const float* __restrict__ bns, const float* __restrict__ bnb,
                const float* __restrict__ bnm, const float* __restrict__ bnv,
                u16* __restrict__ out)
{
    __shared__ __align__(16) unsigned char S[18816];
    float* s_bn = (float*)(S + 18432);

    const int tid = threadIdx.x;
    const int ocg = blockIdx.x & 3;
    const int img = blockIdx.x >> 2;

    const u16* inI = in + (size_t)img * 144 * 64;
    for (int g = tid; g < 144 * 8; g += 256) {
        int pos = g >> 3, part = g & 7;
        int off = (pos * 128 + part * 16) ^ ((pos & 7) << 4);
        *(bf16x8*)(S + off) = *(const bf16x8*)(inI + g * 8);
    }
    if (tid < 32) {
        int oc = ocg * 32 + tid;
        float sc = bns[oc] * rsqrtf(bnv[oc] + 1e-5f);
        s_bn[tid] = cbias[oc]; s_bn[32 + tid] = sc; s_bn[64 + tid] = bnb[oc] - bnm[oc] * sc;
    }
    __syncthreads();

    const int w = tid >> 6, lr = tid & 15, lg = (tid >> 4) & 3;
    f32x4 acc[2][2];
    {
        f32x4 z = {0.f, 0.f, 0.f, 0.f};
        acc[0][0] = z; acc[0][1] = z; acc[1][0] = z; acc[1][1] = z;
    }
    int pb7[2];
    #pragma unroll
    for (int mi = 0; mi < 2; ++mi) {
        int aq = (w + mi * 4) * 4 + (lr >> 2);
        if (aq > 24) aq = 24;
        int y2 = 2 * (aq / 5) + ((lr >> 1) & 1);
        int x2 = 2 * (aq % 5) + (lr & 1);
        pb7[mi] = ((y2 * 12 + x2) << 7) + lg * 16;
    }
    const bf16x8* W4v = (const bf16x8*)W4g;
    const int base = ocg * 2304 + lr * 4 + lg;
    #pragma unroll
    for (int ks = 0; ks < 18; ++ks) {
        bf16x8 b0 = W4v[base + ks * 128];
        bf16x8 b1 = W4v[base + ks * 128 + 64];
        const int cell = ks >> 1;
        const int dp7 = (((cell / 3) * 12 + (cell % 3)) << 7) + (ks & 1) * 64;
        #pragma unroll
        for (int mi = 0; mi < 2; ++mi) {
            int pa = pb7[mi] + dp7;
            int off = pa ^ ((pa >> 3) & 0x70);
            bf16x8 a = *(const bf16x8*)(S + off);
            acc[mi][0] = mfma16(a, b0, acc[mi][0]);
            acc[mi][1] = mfma16(a, b1, acc[mi][1]);
        }
    }
    u16* outI = out + (size_t)img * 3200;
    float bc0 = s_bn[lr],      sc0 = s_bn[32 + lr], sh0 = s_bn[64 + lr];
    float bc1 = s_bn[16 + lr], sc1 = s_bn[48 + lr], sh1 = s_bn[80 + lr];
    #pragma unroll
    for (int mi = 0; mi < 2; ++mi) {
        int quad = (w + mi * 4) * 4 + lg;
        if (quad < 25) {
            float m0 = -3.4e38f, m1 = -3.4e38f;
            #pragma unroll
            for (int r2 = 0; r2 < 4; ++r2) {
                m0 = fmaxf(m0, fmaxf(acc[mi][0][r2] + bc0, 0.f) * sc0 + sh0);
                m1 = fmaxf(m1, fmaxf(acc[mi][1][r2] + bc1, 0.f) * sc1 + sh1);
            }
            outI[(ocg * 32 + lr) * 25 + quad]      = f2bf(m0);
            outI[(ocg * 32 + 16 + lr) * 25 + quad] = f2bf(m1);
        }
    }
}

// ---------------------------------------------------------------------------
// fc GEMM, both operands bf16 (unchanged).
// ---------------------------------------------------------------------------
template<bool OUTF32>
__global__ __launch_bounds__(256)
void fc_gemm_bf(const u16* __restrict__ A, const u16* __restrict__ Wb,
                const float* __restrict__ bias, void* __restrict__ outv,
                int M, int N, int K)
{
    __shared__ __align__(16) unsigned char S[34816];   // sA 64x272 | sB 64x272
    const int tid = threadIdx.x;
    const int n0 = blockIdx.x * 64, m0 = blockIdx.y * 64;
    const int w = tid >> 6, lr = tid & 15, lg = (tid >> 4) & 3;
    const int r = tid >> 2, c = tid & 3;

    f32x4 acc[4];
    { f32x4 z = {0.f,0.f,0.f,0.f}; acc[0]=z; acc[1]=z; acc[2]=z; acc[3]=z; }

    const u16* Ab = A  + (size_t)(m0 + r) * K + c * 8;
    const u16* Bb = Wb + (size_t)(n0 + r) * K + c * 8;
    unsigned char* sAw = S + r * 272 + c * 16;
    unsigned char* sBw = S + 17408 + r * 272 + c * 16;

    for (int k0 = 0; k0 < K; k0 += 128) {
        #pragma unroll
        for (int q = 0; q < 4; ++q) {
            *(bf16x8*)(sAw + q * 64) = *(const bf16x8*)(Ab + k0 + q * 32);
            *(bf16x8*)(sBw + q * 64) = *(const bf16x8*)(Bb + k0 + q * 32);
        }
        __syncthreads();
        #pragma unroll
        for (int k32 = 0; k32 < 4; ++k32) {
            bf16x8 a = *(const bf16x8*)(S + (w * 16 + lr) * 272 + k32 * 64 + lg * 16);
            #pragma unroll
            for (int nt = 0; nt < 4; ++nt) {
                bf16x8 b = *(const bf16x8*)(S + 17408 + (nt * 16 + lr) * 272 + k32 * 64 + lg * 16);
                acc[nt] = mfma16(a, b, acc[nt]);
            }
        }
        __syncthreads();
    }
    #pragma unroll
    for (int nt = 0; nt < 4; ++nt) {
        int col = n0 + nt * 16 + lr;
        float bv = bias[col];
        #pragma unroll
        for (int r2 = 0; r2 < 4; ++r2) {
            int row = m0 + w * 16 + lg * 4 + r2;
            float v = fmaxf(acc[nt][r2] + bv, 0.f);
            if (OUTF32) ((float*)outv)[(size_t)row * N + col] = v;
            else        ((u16*)outv)[(size_t)row * N + col] = f2bf(v);
        }
    }
}

// ---------------------------------------------------------------------------
// Fused fc3 (512->37) + sigmoid + sequential normalize + dep-multiply.
// ---------------------------------------------------------------------------
__global__ __launch_bounds__(256)
void fc3_norm(const float* __restrict__ A, const float* __restrict__ W,
              const float* __restrict__ bias, float* __restrict__ out)
{
    __shared__ float sp[4][40];
    const int v = threadIdx.x >> 6, lane = threadIdx.x & 63;
    const int img = blockIdx.x * 4 + v;

    if (lane < 37) {
        const float4* a4 = (const float4*)(A + (size_t)img * 512);
        const float4* w4 = (const float4*)(W + (size_t)lane * 512);
        float s = bias[lane];
        #pragma unroll 4
        for (int k = 0; k < 128; ++k) {
            float4 a = a4[k], ww = w4[k];
            s = fmaf(a.x, ww.x, s); s = fmaf(a.y, ww.y, s);
            s = fmaf(a.z, ww.z, s); s = fmaf(a.w, ww.w, s);
        }
        sp[v][lane] = 1.f / (1.f + expf(-s));
    }
    __syncthreads();
    if (lane == 0) {
        float xv[37];
        #pragma unroll
        for (int i = 0; i < 37; ++i) xv[i] = sp[v][i];
        const int ss[11]  = {0, 3, 5, 7, 9, 13, 15, 18, 25, 28, 31};
        const int ee[11]  = {3, 5, 7, 9, 13, 15, 18, 25, 28, 31, 37};
        const int dep[11] = {-1, 1, 4, 4, 4, -1, 0, 13, 3, 7, 7};
        #pragma unroll
        for (int i = 0; i < 11; ++i) {
            for (int j = ss[i]; j < ee[i]; ++j) {
                float ssum = 0.f;
                for (int cix = ss[i]; cix < ee[i]; ++cix) ssum += xv[cix];
                xv[j] = xv[j] / (ssum + 1e-12f);
            }
        }
        #pragma unroll
        for (int i = 0; i < 11; ++i) {
            if (dep[i] >= 0) {
                const float m = xv[dep[i]];
                for (int cix = ss[i]; cix < ee[i]; ++cix) xv[cix] *= m;
            }
        }
        #pragma unroll
        for (int i = 0; i < 37; ++i) sp[v][i] = xv[i];
    }
    __syncthreads();
    if (lane < 37) out[(size_t)img * 37 + lane] = sp[v][lane];
}

// ---------------------------------------------------------------------------
extern "C" void kernel_launch(void* const* d_in, const int* in_sizes, int n_in,
                              void* d_out, int out_size, void* d_ws, size_t ws_size,
                              hipStream_t stream)
{
    const float* x   = (const float*)d_in[0];
    const float* c1w = (const float*)d_in[1];  const float* c1b = (const float*)d_in[2];
    const float* b1s = (const float*)d_in[3];  const float* b1b = (const float*)d_in[4];
    const float* b1m = (const float*)d_in[5];  const float* b1v = (const float*)d_in[6];
    const float* c2w = (const float*)d_in[7];  const float* c2b = (const float*)d_in[8];
    const float* b2s = (const float*)d_in[9];  const float* b2b = (const float*)d_in[10];
    const float* b2m = (const float*)d_in[11]; const float* b2v = (const float*)d_in[12];
    const float* c3w = (const float*)d_in[13]; const float* c3b = (const float*)d_in[14];
    const float* b3s = (const float*)d_in[15]; const float* b3b = (const float*)d_in[16];
    const float* b3m = (const float*)d_in[17]; const float* b3v = (const float*)d_in[18];
    const float* c4w = (const float*)d_in[19]; const float* c4b = (const float*)d_in[20];
    const float* b4s = (const float*)d_in[21]; const float* b4b = (const float*)d_in[22];
    const float* b4m = (const float*)d_in[23]; const float* b4v = (const float*)d_in[24];
    const float* f1w = (const float*)d_in[25]; const float* f1b = (const float*)d_in[26];
    const float* f2w = (const float*)d_in[27]; const float* f2b = (const float*)d_in[28];
    const float* f3w = (const float*)d_in[29]; const float* f3b = (const float*)d_in[30];

    // Workspace (bytes), peak 81.74 MB:
    //   P2  bf16 [1024][676][32]  @ 0           44,302,336
    //   Xp  bf16 [1024][3600][4]  @ 44,302,336  29,491,200  (dead after conv12)
    //   P3  bf16 [1024][144][64]  @ 44,302,336  (overlays Xp)
    //   P4  bf16 [1024][3200]     @ 63,176,704  (overlays Xp)
    //   F1  bf16 [1024][1024]     @ 69,730,304  (overlays Xp)
    //   F2  f32  [1024][512]      @ 71,827,456  (overlays Xp tail)
    //   W1b bf16                  @ 73,924,608   6,553,600
    //   W2b bf16                  @ 80,478,208   1,048,576
    //   W1t @81,526,784 (4,096) | W2g @81,530,880 (25,600)
    //   W3g @81,556,480 (36,864) | W4g @81,593,344 (147,456)
    u16*   P2  = (u16*)d_ws;
    u16*   Xp  = (u16*)((char*)d_ws + 44302336);
    u16*   P3  = (u16*)((char*)d_ws + 44302336);
    u16*   P4  = (u16*)((char*)d_ws + 63176704);
    u16*   F1  = (u16*)((char*)d_ws + 69730304);
    float* F2  = (float*)((char*)d_ws + 71827456);
    u16*   W1b = (u16*)((char*)d_ws + 73924608);
    u16*   W2b = (u16*)((char*)d_ws + 80478208);
    u16*   W1t = (u16*)((char*)d_ws + 81526784);
    u16*   W2g = (u16*)((char*)d_ws + 81530880);
    u16*   W3g = (u16*)((char*)d_ws + 81556480);
    u16*   W4g = (u16*)((char*)d_ws + 81593344);

    // prep items = 3,686,400 + 819,200 + 131,072 + 2,048 + 12,800 + 18,432
    //            + 73,728 = 4,743,680 = 256 * 18,530
    prep_all<<<18530, 256, 0, stream>>>(x, c1w, c2w, c3w, c4w, f1w, f2w,
                                        Xp, W1t, W2g, W3g, W4g, W1b, W2b);

    conv12_fused<<<BATCH * 4, 512, 0, stream>>>(Xp, W1t, W2g, c1b, b1s, b1b, b1m, b1v,
                                                c2b, b2s, b2b, b2m, b2v, P2);
    conv3_mfma<<<BATCH * 2, 576, 0, stream>>>(P2, W3g, c3b, b3s, b3b, b3m, b3v, P3);
    conv4_mfma<<<BATCH * 4, 256, 0, stream>>>(P3, W4g, c4b, b4s, b4b, b4m, b4v, P4);

    fc_gemm_bf<false><<<dim3(16, 16), 256, 0, stream>>>(P4, W1b, f1b, F1, 1024, 1024, 3200);
    fc_gemm_bf<true ><<<dim3(8, 16),  256, 0, stream>>>(F1, W2b, f2b, F2, 1024, 512, 1024);
    fc3_norm<<<BATCH / 4, 256, 0, stream>>>(F2, f3w, f3b, (float*)d_out);
}